// Round 10
// baseline (383.079 us; speedup 1.0000x reference)
//
#include <hip/hip_runtime.h>
#include <math.h>

#define HWP 16384   // 128*128 pooled plane

// ---------------- workspace layout (float offsets) ----------------
// Lifetimes (same-stream serialization):
//   pre   [0, 12,582,912)          pool_conv -> dw3x3
//   cov   [0, ~2.12M)              mean -> simsort      (inside dead pre)
//   attn  [0, 4,194,304)           attn -> post         (inside dead pre)
//   out3  [4,194,304, 8,388,608)   post -> final        (inside dead pre)
//   tail  [12,570,112, 12,582,912) idx/inv + MLP weights, written only
//                                  after dw3x3, live through post
//   qkv   [12,582,912, 25,165,824) dw3x3 -> post; READ-ONLY after dw3x3
//                                  (attn no longer writes V planes in
//                                  place -> no inter-tile halo race).
static const size_t PRE_OFF  = 0;          // 12,582,912
static const size_t QKV_OFF  = 12582912;
// wT lives at the START of the QKV region: written by k_prep_wt, read only by
// k_pool_conv (which writes PRE only), then overwritten by k_dw3x3_zero.
static const size_t WT_OFF   = QKV_OFF;    // 12,288 floats
static const size_t COVP_OFF = 0;          // 2,097,152
static const size_t MEAN_OFF = 2097152;    // 256
static const size_t COVS_OFF = 2097408;    // 16,384 -> ends 2,113,792
static const size_t ATTN_OFF = 0;          // 4,194,304 (cov dead by attn)
static const size_t OUT3_OFF = 4194304;    // 4,194,304 -> ends 8,388,608
static const size_t IDX_OFF  = 12570112;   // 256 ints
static const size_t INV_OFF  = 12570368;   // 256 ints
static const size_t GT2_OFF  = 12570624;   // 4096
static const size_t DT2_OFF  = 12574720;   // 2048
static const size_t UT2_OFF  = 12576768;   // 2048
static const size_t PT2_OFF  = 12578816;   // 4096 -> ends 12,582,912 exactly

// ---------------- 0: transpose qkv_w -> wT[c*192+o] ----------------
__global__ __launch_bounds__(256) void k_prep_wt(
    const float* __restrict__ qkv_w, float* __restrict__ wT) {
  int i = blockIdx.x * 256 + threadIdx.x;   // 12288
  int o = i >> 6, c = i & 63;
  wT[c * 192 + o] = qkv_w[i];
}

// ---------------- 0b: transpose MLP weights to d-major ----------------
__global__ __launch_bounds__(256) void k_prep2(
    const float* __restrict__ gating_w, const float* __restrict__ down_w,
    const float* __restrict__ up_w, const float* __restrict__ proj_w,
    float* __restrict__ gT, float* __restrict__ dT,
    float* __restrict__ uT, float* __restrict__ pT) {
  int t = blockIdx.x * 256 + threadIdx.x;
  if (t < 4096) {
    int o = t >> 6, d = t & 63;
    gT[d * 64 + o] = gating_w[t];
    pT[d * 64 + o] = proj_w[t];
  }
  if (t < 2048) {
    int o = t >> 6, d = t & 63;      // down_w (32,64)
    dT[d * 32 + o] = down_w[t];
    int o2 = t >> 5, d2 = t & 31;    // up_w (64,32)
    uT[d2 * 64 + o2] = up_w[t];
  }
}

// ---------------- 1: maxpool2 + conv1x1 (x -> qkv_pre) ----------------
__global__ __launch_bounds__(256) void k_pool_conv(
    const float* __restrict__ x, const float* __restrict__ wT,
    float* __restrict__ pre) {
  int b = blockIdx.x >> 8;          // 256 tiles / batch
  int pix0 = (blockIdx.x & 255) * 64;
  __shared__ float xt[64 * 64];     // [c][p]
  int t = threadIdx.x;
  for (int i = 0; i < 16; ++i) {
    int f = i * 256 + t;
    int c = f >> 6, p = f & 63;
    int pix = pix0 + p;
    int y = pix >> 7, xx = pix & 127;
    const float* src = x + ((size_t)(b * 64 + c) * 65536) + (2 * y) * 256 + 2 * xx;
    float2 v01 = *(const float2*)src;
    float2 v23 = *(const float2*)(src + 256);
    xt[c * 64 + p] = fmaxf(fmaxf(v01.x, v01.y), fmaxf(v23.x, v23.y));
  }
  __syncthreads();
  int p = t & 63;
  int obase = __builtin_amdgcn_readfirstlane((t >> 6) * 48);  // wave-uniform
  const float* wbase = wT + obase;
  float acc[48];
#pragma unroll
  for (int j = 0; j < 48; ++j) acc[j] = 0.f;
  for (int c = 0; c < 64; ++c) {
    float xv = xt[c * 64 + p];
    const float* wc = wbase + c * 192;    // uniform -> s_load_dwordx16 x3
#pragma unroll
    for (int j = 0; j < 48; ++j) acc[j] = fmaf(wc[j], xv, acc[j]);
  }
  float* dst = pre + ((size_t)b * 192 + obase) * HWP + pix0 + p;
#pragma unroll
  for (int j = 0; j < 48; ++j) dst[(size_t)j * HWP] = acc[j];
}

// ---------------- 2: depthwise 3x3, zero pad (pre -> qkv) ----------------
// float4 per thread (4 pixels); boundary zeros fed through the SAME fmaf
// chain order as scalar skip logic -> bitwise-identical output.
__global__ __launch_bounds__(256) void k_dw3x3_zero(
    const float* __restrict__ pre, const float* __restrict__ lce_w,
    float* __restrict__ qkv) {
  int gid = blockIdx.x * 256 + threadIdx.x;   // over 768*128*32 float4s
  int c4 = gid & 31;
  int y  = (gid >> 5) & 127;
  int bc = gid >> 12;                          // b*192 + ch
  int ch = bc % 192;
  int x0 = c4 * 4;
  const float* base = pre + (size_t)bc * HWP;
  const float* w = lce_w + ch * 9;
  const float4 z4 = make_float4(0.f, 0.f, 0.f, 0.f);
  bool ym = y > 0, yp = y < 127;
  bool xl = x0 > 0, xr = x0 < 124;
  const float* rowm = base + (y - 1) * 128;
  const float* rowc = base + y * 128;
  const float* rowp = base + (y + 1) * 128;
  float4 vm = ym ? *(const float4*)(rowm + x0) : z4;
  float  lm = (ym && xl) ? rowm[x0 - 1] : 0.f;
  float  rm = (ym && xr) ? rowm[x0 + 4] : 0.f;
  float4 vc = *(const float4*)(rowc + x0);
  float  lc = xl ? rowc[x0 - 1] : 0.f;
  float  rc = xr ? rowc[x0 + 4] : 0.f;
  float4 vp = yp ? *(const float4*)(rowp + x0) : z4;
  float  lp = (yp && xl) ? rowp[x0 - 1] : 0.f;
  float  rp = (yp && xr) ? rowp[x0 + 4] : 0.f;
  float w0 = w[0], w1 = w[1], w2 = w[2], w3 = w[3], w4 = w[4],
        w5 = w[5], w6 = w[6], w7 = w[7], w8 = w[8];
  float4 o;
  o.x = fmaf(w8, vp.y, fmaf(w7, vp.x, fmaf(w6, lp,
        fmaf(w5, vc.y, fmaf(w4, vc.x, fmaf(w3, lc,
        fmaf(w2, vm.y, fmaf(w1, vm.x, fmaf(w0, lm, 0.f)))))))));
  o.y = fmaf(w8, vp.z, fmaf(w7, vp.y, fmaf(w6, vp.x,
        fmaf(w5, vc.z, fmaf(w4, vc.y, fmaf(w3, vc.x,
        fmaf(w2, vm.z, fmaf(w1, vm.y, fmaf(w0, vm.x, 0.f)))))))));
  o.z = fmaf(w8, vp.w, fmaf(w7, vp.z, fmaf(w6, vp.y,
        fmaf(w5, vc.w, fmaf(w4, vc.z, fmaf(w3, vc.y,
        fmaf(w2, vm.w, fmaf(w1, vm.z, fmaf(w0, vm.y, 0.f)))))))));
  o.w = fmaf(w8, rp,   fmaf(w7, vp.w, fmaf(w6, vp.z,
        fmaf(w5, rc,   fmaf(w4, vc.w, fmaf(w3, vc.z,
        fmaf(w2, rm,   fmaf(w1, vm.w, fmaf(w0, vm.z, 0.f)))))))));
  *(float4*)(qkv + (size_t)bc * HWP + y * 128 + x0) = o;
}

// ---------------- 3a: per-channel mean of q ----------------
__global__ __launch_bounds__(256) void k_mean(
    const float* __restrict__ qkv, float* __restrict__ mean) {
  int bc = blockIdx.x;              // b*64 + c
  int b = bc >> 6, c = bc & 63;
  const float* src = qkv + ((size_t)b * 192 + c) * HWP;
  float s = 0.f;
  for (int i = threadIdx.x; i < HWP; i += 256) s += src[i];
  __shared__ float red[4];
  for (int off = 32; off > 0; off >>= 1) s += __shfl_down(s, off);
  int t = threadIdx.x;
  if ((t & 63) == 0) red[t >> 6] = s;
  __syncthreads();
  if (t == 0) mean[bc] = (red[0] + red[1] + red[2] + red[3]) * (1.f / 16384.f);
}

// ---------------- 3b: centered cov partials (chunks of 128) ----------------
__global__ __launch_bounds__(256) void k_covpart(
    const float* __restrict__ qkv, const float* __restrict__ mean,
    float* __restrict__ covp) {
  int blk = blockIdx.x;             // b*128 + chunk
  int b = blk >> 7, chunk = blk & 127;
  int e0 = chunk * 128;
  __shared__ float qc[64 * 129];    // +1 pad breaks stride conflicts
  int t = threadIdx.x;
  for (int i = 0; i < 32; ++i) {
    int f = i * 256 + t;
    int c = f >> 7, e = f & 127;
    qc[c * 129 + e] = qkv[((size_t)b * 192 + c) * HWP + e0 + e] - mean[b * 64 + c];
  }
  __syncthreads();
  int d = t & 63;
  int crow = t >> 6;                // wave-uniform
  float acc[16];
#pragma unroll
  for (int i = 0; i < 16; ++i) acc[i] = 0.f;
  for (int e = 0; e < 128; ++e) {
    float qd = qc[d * 129 + e];
#pragma unroll
    for (int i = 0; i < 16; ++i) {
      int c = crow + 4 * i;
      acc[i] = fmaf(qc[c * 129 + e], qd, acc[i]);
    }
  }
  float* dst = covp + (size_t)blk * 4096;
#pragma unroll
  for (int i = 0; i < 16; ++i) {
    int c = crow + 4 * i;
    dst[c * 64 + d] = acc[i];       // == dst[i*256 + t], coalesced
  }
}

// ---------------- 3b2: reduce cov partials over 128 chunks ----------------
__global__ __launch_bounds__(256) void k_covred(
    const float* __restrict__ covp, float* __restrict__ covs) {
  int blk = blockIdx.x;             // b*16 + j
  int b = blk >> 4;
  int pp = (blk & 15) * 256 + threadIdx.x;
  const float* src = covp + (size_t)b * 524288 + pp;
  float s = 0.f;
  for (int ch = 0; ch < 128; ++ch) s += src[ch * 4096];   // chunk order preserved
  covs[b * 4096 + pp] = s;
}

// ---------------- 3c: correlation-mean sim, stable rank ----------------
__global__ __launch_bounds__(256) void k_simsort(
    const float* __restrict__ covs_g, int* __restrict__ idx, int* __restrict__ inv) {
  int b = blockIdx.x;               // 4 blocks
  __shared__ float covs[4096];
  __shared__ float stds[64];
  __shared__ float sims[64];
  int t = threadIdx.x;
  for (int i = 0; i < 16; ++i) covs[i * 256 + t] = covs_g[b * 4096 + i * 256 + t];
  __syncthreads();
  if (t < 64) stds[t] = sqrtf(covs[t * 64 + t] + 1e-8f);
  __syncthreads();
  if (t < 64) {
    float s = 0.f;
    float sc = stds[t];
    for (int d2 = 0; d2 < 64; ++d2) {
      float denom = fmaxf(sc * stds[d2], 1e-8f);
      s += covs[d2 * 64 + t] / denom;   // symmetric matrix: bitwise equal to [t][d2]
    }
    sims[t] = s * (1.f / 64.f);
  }
  __syncthreads();
  if (t < 64) {
    float sv = sims[t];
    int r = 0;
    for (int d2 = 0; d2 < 64; ++d2) {
      float o = sims[d2];
      if (o > sv || (o == sv && d2 < t)) r++;
    }
    idx[b * 64 + r] = t;
    inv[b * 64 + t] = r;
  }
}

// ---------------- 7: FUSED stage + halo block attention + gate ----------
// Round-10: 4 waves per tile (256 threads), 25 keys/wave. r9 counters:
// VALU-busy time 31.6us == the 28.7us VALU-issue floor (8 waves/SIMD x
// ~8600 cyc), but dur 55.4us -> 43% idle at ~5 resident blocks/CU
// (occupancy 30%). Quadrupling waves/block closes the idle gap toward the
// floor; LDS 17.4KB caps 9 blocks/CU x 4 waves = 36 > 32 = HW max.
// Inner loop needs no py/px (OOB rows zero-staged) -> walk keys linearly.
// Gate work also drops 8->4 outputs per wave. 4-way softmax partial
// reassociation, same class as r4/r5 splits (absmax unchanged there).
#define KVP 20   // padded row stride: 80B, gcd(20,32)=4 -> 8 bank groups
__global__ __launch_bounds__(256) void k_attn(
    const float* __restrict__ qkv, const int* __restrict__ idx,
    const float* __restrict__ rel_h, const float* __restrict__ rel_w,
    const float* __restrict__ gate_w, const float* __restrict__ gate_b,
    const float* __restrict__ temp, float* __restrict__ attn_out) {
  int bi = blockIdx.x;
  int head = bi & 3;
  int wj = (bi >> 2) & 15;
  int hi = (bi >> 6) & 15;
  int b = bi >> 10;
  int tt = threadIdx.x;                            // 0..255
  int t = tt & 63;                                 // lane = query
  int w = __builtin_amdgcn_readfirstlane(tt >> 6); // wave 0..3
  // staging: kr[100][KVP] | vr[100][KVP] = 4000 floats
  // combine (after barrier, overlays): po[4][16][64]=4096 + pw[4][64]=256
  __shared__ __align__(16) float smem[4352];       // 17,408 B
  float* kr = smem;
  float* vr = smem + 100 * KVP;
  const size_t bb = (size_t)b * 192 * HWP;
  int chg[16];
#pragma unroll
  for (int ch = 0; ch < 16; ++ch) chg[ch] = idx[b * 64 + head * 16 + ch];
  // ---- fused staging: one halo position per thread (waves 0-1) ----
  if (tt < 100) {
    int py = tt / 10, px = tt - py * 10;
    int ky = hi * 8 + py - 1, kx = wj * 8 + px - 1;
    bool ok = (ky >= 0) && (ky < 128) && (kx >= 0) && (kx < 128);
    int sp = ky * 128 + kx;
    float kv[16];
    float s = 0.f;
#pragma unroll
    for (int ch = 0; ch < 16; ++ch) {
      float k = ok ? qkv[bb + (size_t)(64 + chg[ch]) * HWP + sp] : 0.f;
      k += (ch < 8) ? rel_h[(head * 10 + py) * 8 + ch]
                    : rel_w[(head * 10 + px) * 8 + (ch - 8)];
      kv[ch] = k;
      s += k * k;
    }
    float rn = 1.f / fmaxf(sqrtf(s), 1e-12f);     // ref: l2norm(k+rel) pre-dot
    float4* krow = (float4*)(kr + tt * KVP);
    krow[0] = make_float4(kv[0] * rn,  kv[1] * rn,  kv[2] * rn,  kv[3] * rn);
    krow[1] = make_float4(kv[4] * rn,  kv[5] * rn,  kv[6] * rn,  kv[7] * rn);
    krow[2] = make_float4(kv[8] * rn,  kv[9] * rn,  kv[10] * rn, kv[11] * rn);
    krow[3] = make_float4(kv[12] * rn, kv[13] * rn, kv[14] * rn, kv[15] * rn);
    float vv[16];
#pragma unroll
    for (int ch = 0; ch < 16; ++ch)
      vv[ch] = ok ? qkv[bb + (size_t)(128 + chg[ch]) * HWP + sp] : 0.f;
    float4* vrow = (float4*)(vr + tt * KVP);
    vrow[0] = make_float4(vv[0],  vv[1],  vv[2],  vv[3]);
    vrow[1] = make_float4(vv[4],  vv[5],  vv[6],  vv[7]);
    vrow[2] = make_float4(vv[8],  vv[9],  vv[10], vv[11]);
    vrow[3] = make_float4(vv[12], vv[13], vv[14], vv[15]);
  }
  // ---- per-query q (overlaps staging latency) ----
  int qy = hi * 8 + (t >> 3), qx = wj * 8 + (t & 7);
  float q[16];
  float qs = 0.f;
#pragma unroll
  for (int ch = 0; ch < 16; ++ch) {
    q[ch] = qkv[bb + (size_t)chg[ch] * HWP + qy * 128 + qx];
    qs += q[ch] * q[ch];
  }
  float T = expf(temp[head]);
  float qnT = T / fmaxf(sqrtf(qs), 1e-12f);
  __syncthreads();
  // ---- 25 keys per wave, all operands from LDS broadcasts ----
  float out[16];
#pragma unroll
  for (int ch = 0; ch < 16; ++ch) out[ch] = 0.f;
  float wsum = 0.f;
  {
    const float* kp = kr + (w * 25) * KVP;
    const float* vp = vr + (w * 25) * KVP;
    for (int i = 0; i < 25; ++i) {
      float d0 = 0.f, d1 = 0.f, d2 = 0.f, d3 = 0.f;
#pragma unroll
      for (int ch = 0; ch < 4; ++ch) {
        d0 = fmaf(q[ch], kp[ch], d0);
        d1 = fmaf(q[ch + 4], kp[ch + 4], d1);
        d2 = fmaf(q[ch + 8], kp[ch + 8], d2);
        d3 = fmaf(q[ch + 12], kp[ch + 12], d3);
      }
      float dacc = (d0 + d1) + (d2 + d3);
      float e = __expf(fmaf(dacc, qnT, -T));      // exp(d - T): exact softmax shift
      wsum += e;                                  // OOB keys count in denominator
#pragma unroll
      for (int ch = 0; ch < 16; ++ch)
        out[ch] = fmaf(e, vp[ch], out[ch]);       // OOB rows are zero -> no mask
      kp += KVP;
      vp += KVP;
    }
  }
  // ---- cross-wave combine: po/pw overlay the dead kr/vr region ----
  __syncthreads();                 // all waves done reading kr/vr
  float* po = smem;                // [4][16][64] = 4096 floats
  float* pwp = smem + 4096;        // [4][64] -> ends 4352
  pwp[w * 64 + t] = wsum;
#pragma unroll
  for (int ch = 0; ch < 16; ++ch) po[(w * 16 + ch) * 64 + t] = out[ch];
  __syncthreads();
  float winv = 1.f / (((pwp[t] + pwp[64 + t]) + pwp[128 + t]) + pwp[192 + t]);
  int ob = w * 4;                                 // this wave's 4 outputs
#pragma unroll
  for (int i = 0; i < 4; ++i) {
    int o = ob + i;
    float oc = ((po[o * 64 + t] + po[(16 + o) * 64 + t])
              + po[(32 + o) * 64 + t]) + po[(48 + o) * 64 + t];
    float gsv = gate_b[head * 16 + o];
#pragma unroll
    for (int c = 0; c < 16; ++c)
      gsv = fmaf(gate_w[head * 256 + o * 16 + c], q[c], gsv);
    float sig = 1.f / (1.f + __expf(-gsv));
    attn_out[((size_t)b * 64 + chg[o]) * HWP + qy * 128 + qx] = oc * winv * sig;
  }
}

// ---------------- 8: mixed -> gating -> down -> up -> (+attn) -> proj ----
// attn lives in its own buffer: channel c of batch b at (b*64+c)*HWP.
// 256 threads = 4 waves per block, 64 pixels per block (lane = pixel).
// Output channels are SPLIT ACROSS WAVES (16/wave; 8/wave for down).
// Per-channel accumulator chain order (d ascending) unchanged -> bitwise-
// identical results.
__global__ __launch_bounds__(256) void k_post(
    const float* __restrict__ attn, const float* __restrict__ qkv,
    const float* __restrict__ gT, const float* __restrict__ gating_b,
    const float* __restrict__ dT, const float* __restrict__ down_b,
    const float* __restrict__ uT, const float* __restrict__ up_b,
    const float* __restrict__ pT, float* __restrict__ out3) {
  __shared__ float xs[64 * 64];     // [c][pix]
  int t = threadIdx.x;
  int lane = t & 63;                // pixel within block
  int w = t >> 6;                   // wave 0..3 (uniform)
  int p = blockIdx.x * 64 + lane;   // global pooled pixel id
  int b = p >> 14;
  int pix = p & 16383;
  const float* ap = attn + (size_t)b * 64 * HWP + pix;
  const float* qp = qkv + (size_t)b * 192 * HWP + pix;
  float* op = out3 + (size_t)b * 64 * HWP + pix;
  int ob16 = __builtin_amdgcn_readfirstlane(w * 16);
  int ob8  = __builtin_amdgcn_readfirstlane(w * 8);
  // mixed = attn_out + (q + k): each wave loads its 16 channels (concurrent)
#pragma unroll
  for (int i = 0; i < 16; ++i) {
    int c = ob16 + i;
    xs[c * 64 + lane] = ap[(size_t)c * HWP] + qp[(size_t)c * HWP] + qp[(size_t)(64 + c) * HWP];
  }
  __syncthreads();
  // ---- gating conv + exact gelu, * mixed ----
  {
    float acc[16];
#pragma unroll
    for (int o = 0; o < 16; ++o) acc[o] = gating_b[ob16 + o];
    for (int d = 0; d < 64; ++d) {
      float xv = xs[d * 64 + lane];
      const float* wd = gT + d * 64 + ob16;   // wave-uniform -> s_load
#pragma unroll
      for (int o = 0; o < 16; ++o) acc[o] = fmaf(wd[o], xv, acc[o]);
    }
    __syncthreads();                 // all reads done before any overwrite
#pragma unroll
    for (int o = 0; o < 16; ++o) {
      float a = acc[o];
      float ge = 0.5f * a * (1.f + erff(a * 0.70710678118654752f));
      xs[(ob16 + o) * 64 + lane] = ge * xs[(ob16 + o) * 64 + lane];
    }
    __syncthreads();
  }
  // ---- down 64->32 (8 outputs/wave) ----
  {
    float acc[8];
#pragma unroll
    for (int o = 0; o < 8; ++o) acc[o] = down_b[ob8 + o];
    for (int d = 0; d < 64; ++d) {
      float xv = xs[d * 64 + lane];
      const float* wd = dT + d * 32 + ob8;
#pragma unroll
      for (int o = 0; o < 8; ++o) acc[o] = fmaf(wd[o], xv, acc[o]);
    }
    __syncthreads();
#pragma unroll
    for (int o = 0; o < 8; ++o) xs[(ob8 + o) * 64 + lane] = acc[o];
    __syncthreads();
  }
  // ---- up 32->64, + attn residual ----
  {
    float acc[16];
#pragma unroll
    for (int o = 0; o < 16; ++o) acc[o] = up_b[ob16 + o];
    for (int d = 0; d < 32; ++d) {
      float xv = xs[d * 64 + lane];
      const float* wd = uT + d * 64 + ob16;
#pragma unroll
      for (int o = 0; o < 16; ++o) acc[o] = fmaf(wd[o], xv, acc[o]);
    }
    __syncthreads();
#pragma unroll
    for (int o = 0; o < 16; ++o)
      xs[(ob16 + o) * 64 + lane] = acc[o] + ap[(size_t)(ob16 + o) * HWP];
    __syncthreads();
  }
  // ---- proj (no bias) ----
  {
    float acc[16];
#pragma unroll
    for (int o = 0; o < 16; ++o) acc[o] = 0.f;
    for (int d = 0; d < 64; ++d) {
      float xv = xs[d * 64 + lane];
      const float* wd = pT + d * 64 + ob16;
#pragma unroll
      for (int o = 0; o < 16; ++o) acc[o] = fmaf(wd[o], xv, acc[o]);
    }
#pragma unroll
    for (int o = 0; o < 16; ++o) op[(size_t)(ob16 + o) * HWP] = acc[o];
  }
}

// ---------------- 9: dw3x3 reflect + bias + bilinear x2 (align-corners) ----
__global__ __launch_bounds__(256) void k_final(
    const float* __restrict__ out3, const float* __restrict__ lp_w,
    const float* __restrict__ lp_b, float* __restrict__ out) {
  int bi = blockIdx.x;                 // (b*64+ch)*8 + rt
  int rt = bi & 7;
  int bc = bi >> 3;
  int ch = bc & 63;
  int r0 = rt * 16;
  __shared__ float tin[20 * 128];      // input rows r0-2 .. r0+17 (reflected)
  __shared__ float tdw[18 * 128];      // dw rows r0-1 .. r0+16
  int t = threadIdx.x;
  const float* src = out3 + (size_t)bc * HWP;
  for (int i = 0; i < 10; ++i) {
    int f = i * 256 + t;               // 2560 exactly
    int r = f >> 7, xx = f & 127;
    int ry = r0 - 2 + r;
    ry = ry < 0 ? -ry : (ry > 127 ? 254 - ry : ry);
    tin[f] = src[ry * 128 + xx];
  }
  __syncthreads();
  float w0 = lp_w[ch * 9 + 0], w1 = lp_w[ch * 9 + 1], w2 = lp_w[ch * 9 + 2];
  float w3 = lp_w[ch * 9 + 3], w4 = lp_w[ch * 9 + 4], w5 = lp_w[ch * 9 + 5];
  float w6 = lp_w[ch * 9 + 6], w7 = lp_w[ch * 9 + 7], w8 = lp_w[ch * 9 + 8];
  float bias = lp_b[ch];
  for (int i = 0; i < 9; ++i) {
    int f = i * 256 + t;               // 2304 exactly
    int r = f >> 7, xx = f & 127;
    int xm = (xx == 0) ? 1 : xx - 1;
    int xp = (xx == 127) ? 126 : xx + 1;
    const float* r0p = tin + r * 128;
    const float* r1p = r0p + 128;
    const float* r2p = r1p + 128;
    float acc = bias;
    acc = fmaf(w0, r0p[xm], acc); acc = fmaf(w1, r0p[xx], acc); acc = fmaf(w2, r0p[xp], acc);
    acc = fmaf(w3, r1p[xm], acc); acc = fmaf(w4, r1p[xx], acc); acc = fmaf(w5, r1p[xp], acc);
    acc = fmaf(w6, r2p[xm], acc); acc = fmaf(w7, r2p[xx], acc); acc = fmaf(w8, r2p[xp], acc);
    tdw[f] = acc;
  }
  __syncthreads();
  const float s = (float)(127.0 / 255.0);
  float* dst = out + (size_t)bc * 65536;
  for (int i = 0; i < 32; ++i) {
    int f = i * 256 + t;               // 8192 exactly: rows 2r0..2r0+31, cols 0..255
    int vr = f >> 8, vx = f & 255;
    int v = 2 * r0 + vr;
    float cy = (float)v * s;
    int ly = (int)floorf(cy); if (ly > 126) ly = 126;
    float wy = cy - (float)ly;
    float cx = (float)vx * s;
    int lx = (int)floorf(cx); if (lx > 126) lx = 126;
    float wx = cx - (float)lx;
    int lr = ly - r0 + 1;              // tdw row index
    float a  = tdw[lr * 128 + lx];
    float bq = tdw[lr * 128 + lx + 1];
    float c2 = tdw[(lr + 1) * 128 + lx];
    float d2 = tdw[(lr + 1) * 128 + lx + 1];
    float t0 = a  * (1.f - wy) + c2 * wy;   // y-lerp first (matches ref order)
    float t1 = bq * (1.f - wy) + d2 * wy;
    dst[v * 256 + vx] = t0 * (1.f - wx) + t1 * wx;
  }
}

extern "C" void kernel_launch(void* const* d_in, const int* in_sizes, int n_in,
                              void* d_out, int out_size, void* d_ws, size_t ws_size,
                              hipStream_t stream) {
  (void)in_sizes; (void)n_in; (void)out_size; (void)ws_size;
  const float* x        = (const float*)d_in[0];
  const float* qkv_w    = (const float*)d_in[1];
  const float* lce_w    = (const float*)d_in[2];
  const float* gate_w   = (const float*)d_in[3];
  const float* gate_b   = (const float*)d_in[4];
  const float* temp     = (const float*)d_in[5];
  const float* rel_h    = (const float*)d_in[6];
  const float* rel_w    = (const float*)d_in[7];
  const float* down_w   = (const float*)d_in[8];
  const float* down_b   = (const float*)d_in[9];
  const float* up_w     = (const float*)d_in[10];
  const float* up_b     = (const float*)d_in[11];
  const float* gating_w = (const float*)d_in[12];
  const float* gating_b = (const float*)d_in[13];
  const float* proj_w   = (const float*)d_in[14];
  const float* lp_w     = (const float*)d_in[15];
  const float* lp_b     = (const float*)d_in[16];
  float* fws = (float*)d_ws;
  float* outp = (float*)d_out;

  float* pre  = fws + PRE_OFF;
  float* qkv  = fws + QKV_OFF;
  float* attn = fws + ATTN_OFF;
  float* out3 = fws + OUT3_OFF;
  float* covp = fws + COVP_OFF;
  float* mean = fws + MEAN_OFF;
  int* idx = (int*)(fws + IDX_OFF);
  int* inv = (int*)(fws + INV_OFF);
  float* covs = fws + COVS_OFF;
  float* wT   = fws + WT_OFF;
  float* gT   = fws + GT2_OFF;
  float* dT   = fws + DT2_OFF;
  float* uT   = fws + UT2_OFF;
  float* pT   = fws + PT2_OFF;

  k_prep_wt<<<48, 256, 0, stream>>>(qkv_w, wT);
  k_pool_conv<<<1024, 256, 0, stream>>>(x, wT, pre);
  k_dw3x3_zero<<<12288, 256, 0, stream>>>(pre, lce_w, qkv);
  k_prep2<<<16, 256, 0, stream>>>(gating_w, down_w, up_w, proj_w, gT, dT, uT, pT);
  k_mean<<<256, 256, 0, stream>>>(qkv, mean);
  k_covpart<<<512, 256, 0, stream>>>(qkv, mean, covp);
  k_covred<<<64, 256, 0, stream>>>(covp, covs);
  k_simsort<<<4, 256, 0, stream>>>(covs, idx, inv);
  k_attn<<<4096, 256, 0, stream>>>(qkv, idx, rel_h, rel_w, gate_w, gate_b, temp, attn);
  k_post<<<1024, 256, 0, stream>>>(attn, qkv, gT, gating_b, dT, down_b,
                                   uT, up_b, pT, out3);
  k_final<<<2048, 256, 0, stream>>>(out3, lp_w, lp_b, outp);
  (void)inv;
}

// Round 11
// 378.143 us; speedup vs baseline: 1.0131x; 1.0131x over previous
//
#include <hip/hip_runtime.h>
#include <math.h>

#define HWP 16384   // 128*128 pooled plane

// ---------------- workspace layout (float offsets) ----------------
// Lifetimes (same-stream serialization):
//   pre   [0, 12,582,912)          pool_conv -> dw3x3
//   cov   [0, ~2.12M)              mean -> simsort      (inside dead pre)
//   attn  [0, 4,194,304)           attn -> post         (inside dead pre)
//   out3  [4,194,304, 8,388,608)   post -> final        (inside dead pre)
//   tail  [12,570,112, 12,582,912) idx/inv + MLP weights, written only
//                                  after dw3x3, live through post
//   qkv   [12,582,912, 25,165,824) dw3x3 -> post; READ-ONLY after dw3x3
static const size_t PRE_OFF  = 0;          // 12,582,912
static const size_t QKV_OFF  = 12582912;
// wT lives at the START of the QKV region: written by k_prep_wt, read only by
// k_pool_conv (which writes PRE only), then overwritten by k_dw3x3_zero.
static const size_t WT_OFF   = QKV_OFF;    // 12,288 floats
static const size_t COVP_OFF = 0;          // 2,097,152
static const size_t MEAN_OFF = 2097152;    // 256
static const size_t COVS_OFF = 2097408;    // 16,384 -> ends 2,113,792
static const size_t ATTN_OFF = 0;          // 4,194,304 (cov dead by attn)
static const size_t OUT3_OFF = 4194304;    // 4,194,304 -> ends 8,388,608
static const size_t IDX_OFF  = 12570112;   // 256 ints
static const size_t INV_OFF  = 12570368;   // 256 ints
static const size_t GT2_OFF  = 12570624;   // 4096
static const size_t DT2_OFF  = 12574720;   // 2048
static const size_t UT2_OFF  = 12576768;   // 2048
static const size_t PT2_OFF  = 12578816;   // 4096 -> ends 12,582,912 exactly

// ---------------- 0: transpose qkv_w -> wT[c*192+o] ----------------
__global__ __launch_bounds__(256) void k_prep_wt(
    const float* __restrict__ qkv_w, float* __restrict__ wT) {
  int i = blockIdx.x * 256 + threadIdx.x;   // 12288
  int o = i >> 6, c = i & 63;
  wT[c * 192 + o] = qkv_w[i];
}

// ---------------- 0b: transpose MLP weights to d-major ----------------
__global__ __launch_bounds__(256) void k_prep2(
    const float* __restrict__ gating_w, const float* __restrict__ down_w,
    const float* __restrict__ up_w, const float* __restrict__ proj_w,
    float* __restrict__ gT, float* __restrict__ dT,
    float* __restrict__ uT, float* __restrict__ pT) {
  int t = blockIdx.x * 256 + threadIdx.x;
  if (t < 4096) {
    int o = t >> 6, d = t & 63;
    gT[d * 64 + o] = gating_w[t];
    pT[d * 64 + o] = proj_w[t];
  }
  if (t < 2048) {
    int o = t >> 6, d = t & 63;      // down_w (32,64)
    dT[d * 32 + o] = down_w[t];
    int o2 = t >> 5, d2 = t & 31;    // up_w (64,32)
    uT[d2 * 64 + o2] = up_w[t];
  }
}

// ---------------- 1: maxpool2 + conv1x1 (x -> qkv_pre) ----------------
// Round-11: x loads float2 -> float4 (each thread pools TWO adjacent output
// pixels from two 16B row segments): 32 -> 16 VMEM loads/thread at the
// 16B/lane coalescing sweet spot; lane addresses contiguous -> 1KB/instr.
// fmax tree per pixel unchanged -> bitwise-identical pre.
__global__ __launch_bounds__(256) void k_pool_conv(
    const float* __restrict__ x, const float* __restrict__ wT,
    float* __restrict__ pre) {
  int b = blockIdx.x >> 8;          // 256 tiles / batch
  int pix0 = (blockIdx.x & 255) * 64;
  __shared__ float xt[64 * 64];     // [c][p]
  int t = threadIdx.x;
  for (int i = 0; i < 8; ++i) {
    int f = i * 256 + t;            // 2048 = 64c * 32 pixel-pairs
    int c = f >> 5, pp = (f & 31) * 2;
    int pix = pix0 + pp;            // pix0 is 64-aligned -> pair in one row
    int y = pix >> 7, xx = pix & 127;   // xx even -> 2*xx*4B is 16B-aligned
    const float* src = x + ((size_t)(b * 64 + c) * 65536) + (2 * y) * 256 + 2 * xx;
    float4 r0 = *(const float4*)src;
    float4 r1 = *(const float4*)(src + 256);
    xt[c * 64 + pp]     = fmaxf(fmaxf(r0.x, r0.y), fmaxf(r1.x, r1.y));
    xt[c * 64 + pp + 1] = fmaxf(fmaxf(r0.z, r0.w), fmaxf(r1.z, r1.w));
  }
  __syncthreads();
  int p = t & 63;
  int obase = __builtin_amdgcn_readfirstlane((t >> 6) * 48);  // wave-uniform
  const float* wbase = wT + obase;
  float acc[48];
#pragma unroll
  for (int j = 0; j < 48; ++j) acc[j] = 0.f;
  for (int c = 0; c < 64; ++c) {
    float xv = xt[c * 64 + p];
    const float* wc = wbase + c * 192;    // uniform -> s_load_dwordx16 x3
#pragma unroll
    for (int j = 0; j < 48; ++j) acc[j] = fmaf(wc[j], xv, acc[j]);
  }
  float* dst = pre + ((size_t)b * 192 + obase) * HWP + pix0 + p;
#pragma unroll
  for (int j = 0; j < 48; ++j) dst[(size_t)j * HWP] = acc[j];
}

// ---------------- 2: depthwise 3x3, zero pad (pre -> qkv) ----------------
// float4 per thread (4 pixels); boundary zeros fed through the SAME fmaf
// chain order as scalar skip logic -> bitwise-identical output.
__global__ __launch_bounds__(256) void k_dw3x3_zero(
    const float* __restrict__ pre, const float* __restrict__ lce_w,
    float* __restrict__ qkv) {
  int gid = blockIdx.x * 256 + threadIdx.x;   // over 768*128*32 float4s
  int c4 = gid & 31;
  int y  = (gid >> 5) & 127;
  int bc = gid >> 12;                          // b*192 + ch
  int ch = bc % 192;
  int x0 = c4 * 4;
  const float* base = pre + (size_t)bc * HWP;
  const float* w = lce_w + ch * 9;
  const float4 z4 = make_float4(0.f, 0.f, 0.f, 0.f);
  bool ym = y > 0, yp = y < 127;
  bool xl = x0 > 0, xr = x0 < 124;
  const float* rowm = base + (y - 1) * 128;
  const float* rowc = base + y * 128;
  const float* rowp = base + (y + 1) * 128;
  float4 vm = ym ? *(const float4*)(rowm + x0) : z4;
  float  lm = (ym && xl) ? rowm[x0 - 1] : 0.f;
  float  rm = (ym && xr) ? rowm[x0 + 4] : 0.f;
  float4 vc = *(const float4*)(rowc + x0);
  float  lc = xl ? rowc[x0 - 1] : 0.f;
  float  rc = xr ? rowc[x0 + 4] : 0.f;
  float4 vp = yp ? *(const float4*)(rowp + x0) : z4;
  float  lp = (yp && xl) ? rowp[x0 - 1] : 0.f;
  float  rp = (yp && xr) ? rowp[x0 + 4] : 0.f;
  float w0 = w[0], w1 = w[1], w2 = w[2], w3 = w[3], w4 = w[4],
        w5 = w[5], w6 = w[6], w7 = w[7], w8 = w[8];
  float4 o;
  o.x = fmaf(w8, vp.y, fmaf(w7, vp.x, fmaf(w6, lp,
        fmaf(w5, vc.y, fmaf(w4, vc.x, fmaf(w3, lc,
        fmaf(w2, vm.y, fmaf(w1, vm.x, fmaf(w0, lm, 0.f)))))))));
  o.y = fmaf(w8, vp.z, fmaf(w7, vp.y, fmaf(w6, vp.x,
        fmaf(w5, vc.z, fmaf(w4, vc.y, fmaf(w3, vc.x,
        fmaf(w2, vm.z, fmaf(w1, vm.y, fmaf(w0, vm.x, 0.f)))))))));
  o.z = fmaf(w8, vp.w, fmaf(w7, vp.z, fmaf(w6, vp.y,
        fmaf(w5, vc.w, fmaf(w4, vc.z, fmaf(w3, vc.y,
        fmaf(w2, vm.w, fmaf(w1, vm.z, fmaf(w0, vm.y, 0.f)))))))));
  o.w = fmaf(w8, rp,   fmaf(w7, vp.w, fmaf(w6, vp.z,
        fmaf(w5, rc,   fmaf(w4, vc.w, fmaf(w3, vc.z,
        fmaf(w2, rm,   fmaf(w1, vm.w, fmaf(w0, vm.z, 0.f)))))))));
  *(float4*)(qkv + (size_t)bc * HWP + y * 128 + x0) = o;
}

// ---------------- 3a: per-channel mean of q ----------------
__global__ __launch_bounds__(256) void k_mean(
    const float* __restrict__ qkv, float* __restrict__ mean) {
  int bc = blockIdx.x;              // b*64 + c
  int b = bc >> 6, c = bc & 63;
  const float* src = qkv + ((size_t)b * 192 + c) * HWP;
  float s = 0.f;
  for (int i = threadIdx.x; i < HWP; i += 256) s += src[i];
  __shared__ float red[4];
  for (int off = 32; off > 0; off >>= 1) s += __shfl_down(s, off);
  int t = threadIdx.x;
  if ((t & 63) == 0) red[t >> 6] = s;
  __syncthreads();
  if (t == 0) mean[bc] = (red[0] + red[1] + red[2] + red[3]) * (1.f / 16384.f);
}

// ---------------- 3b: centered cov partials (chunks of 128) ----------------
__global__ __launch_bounds__(256) void k_covpart(
    const float* __restrict__ qkv, const float* __restrict__ mean,
    float* __restrict__ covp) {
  int blk = blockIdx.x;             // b*128 + chunk
  int b = blk >> 7, chunk = blk & 127;
  int e0 = chunk * 128;
  __shared__ float qc[64 * 129];    // +1 pad breaks stride conflicts
  int t = threadIdx.x;
  for (int i = 0; i < 32; ++i) {
    int f = i * 256 + t;
    int c = f >> 7, e = f & 127;
    qc[c * 129 + e] = qkv[((size_t)b * 192 + c) * HWP + e0 + e] - mean[b * 64 + c];
  }
  __syncthreads();
  int d = t & 63;
  int crow = t >> 6;                // wave-uniform
  float acc[16];
#pragma unroll
  for (int i = 0; i < 16; ++i) acc[i] = 0.f;
  for (int e = 0; e < 128; ++e) {
    float qd = qc[d * 129 + e];
#pragma unroll
    for (int i = 0; i < 16; ++i) {
      int c = crow + 4 * i;
      acc[i] = fmaf(qc[c * 129 + e], qd, acc[i]);
    }
  }
  float* dst = covp + (size_t)blk * 4096;
#pragma unroll
  for (int i = 0; i < 16; ++i) {
    int c = crow + 4 * i;
    dst[c * 64 + d] = acc[i];       // == dst[i*256 + t], coalesced
  }
}

// ---------------- 3b2: reduce cov partials over 128 chunks ----------------
__global__ __launch_bounds__(256) void k_covred(
    const float* __restrict__ covp, float* __restrict__ covs) {
  int blk = blockIdx.x;             // b*16 + j
  int b = blk >> 4;
  int pp = (blk & 15) * 256 + threadIdx.x;
  const float* src = covp + (size_t)b * 524288 + pp;
  float s = 0.f;
  for (int ch = 0; ch < 128; ++ch) s += src[ch * 4096];   // chunk order preserved
  covs[b * 4096 + pp] = s;
}

// ---------------- 3c: correlation-mean sim, stable rank ----------------
__global__ __launch_bounds__(256) void k_simsort(
    const float* __restrict__ covs_g, int* __restrict__ idx, int* __restrict__ inv) {
  int b = blockIdx.x;               // 4 blocks
  __shared__ float covs[4096];
  __shared__ float stds[64];
  __shared__ float sims[64];
  int t = threadIdx.x;
  for (int i = 0; i < 16; ++i) covs[i * 256 + t] = covs_g[b * 4096 + i * 256 + t];
  __syncthreads();
  if (t < 64) stds[t] = sqrtf(covs[t * 64 + t] + 1e-8f);
  __syncthreads();
  if (t < 64) {
    float s = 0.f;
    float sc = stds[t];
    for (int d2 = 0; d2 < 64; ++d2) {
      float denom = fmaxf(sc * stds[d2], 1e-8f);
      s += covs[d2 * 64 + t] / denom;   // symmetric matrix: bitwise equal to [t][d2]
    }
    sims[t] = s * (1.f / 64.f);
  }
  __syncthreads();
  if (t < 64) {
    float sv = sims[t];
    int r = 0;
    for (int d2 = 0; d2 < 64; ++d2) {
      float o = sims[d2];
      if (o > sv || (o == sv && d2 < t)) r++;
    }
    idx[b * 64 + r] = t;
    inv[b * 64 + t] = r;
  }
}

// ---------------- 7: FUSED stage + halo block attention + gate ----------
// REVERTED to the round-9 2-wave version (proven 55.4us, conflicts 0).
// Round-10 post-mortem: 4-wave split raised occupancy 30->52% but raised
// VALU-busy time 31.6->40us (per-wave q-gather + addr math duplicated 2x)
// and dur 55.4->69. Per-wave fixed work scales with wave count; 2 waves is
// the empirical optimum for this structure. Busy time 31.6us == the fp32
// VALU floor for this algorithm (no fp32 MFMA on CDNA4).
#define KVP 20   // padded row stride: 80B, gcd(20,32)=4 -> 8 bank groups
__global__ __launch_bounds__(128) void k_attn(
    const float* __restrict__ qkv, const int* __restrict__ idx,
    const float* __restrict__ rel_h, const float* __restrict__ rel_w,
    const float* __restrict__ gate_w, const float* __restrict__ gate_b,
    const float* __restrict__ temp, float* __restrict__ attn_out) {
  int bi = blockIdx.x;
  int head = bi & 3;
  int wj = (bi >> 2) & 15;
  int hi = (bi >> 6) & 15;
  int b = bi >> 10;
  int tt = threadIdx.x;                            // 0..127
  int t = tt & 63;                                 // lane = query
  int w = __builtin_amdgcn_readfirstlane(tt >> 6); // wave 0/1
  __shared__ __align__(16) float smem[2 * 100 * KVP];  // kr | vr, 16000 B
  float* kr = smem;
  float* vr = smem + 100 * KVP;
  const size_t bb = (size_t)b * 192 * HWP;
  int chg[16];
#pragma unroll
  for (int ch = 0; ch < 16; ++ch) chg[ch] = idx[b * 64 + head * 16 + ch];
  // ---- fused staging: one halo position per thread ----
  if (tt < 100) {
    int py = tt / 10, px = tt - py * 10;
    int ky = hi * 8 + py - 1, kx = wj * 8 + px - 1;
    bool ok = (ky >= 0) && (ky < 128) && (kx >= 0) && (kx < 128);
    int sp = ky * 128 + kx;
    float kv[16];
    float s = 0.f;
#pragma unroll
    for (int ch = 0; ch < 16; ++ch) {
      float k = ok ? qkv[bb + (size_t)(64 + chg[ch]) * HWP + sp] : 0.f;
      k += (ch < 8) ? rel_h[(head * 10 + py) * 8 + ch]
                    : rel_w[(head * 10 + px) * 8 + (ch - 8)];
      kv[ch] = k;
      s += k * k;
    }
    float rn = 1.f / fmaxf(sqrtf(s), 1e-12f);     // ref: l2norm(k+rel) pre-dot
    float4* krow = (float4*)(kr + tt * KVP);
    krow[0] = make_float4(kv[0] * rn,  kv[1] * rn,  kv[2] * rn,  kv[3] * rn);
    krow[1] = make_float4(kv[4] * rn,  kv[5] * rn,  kv[6] * rn,  kv[7] * rn);
    krow[2] = make_float4(kv[8] * rn,  kv[9] * rn,  kv[10] * rn, kv[11] * rn);
    krow[3] = make_float4(kv[12] * rn, kv[13] * rn, kv[14] * rn, kv[15] * rn);
    float vv[16];
#pragma unroll
    for (int ch = 0; ch < 16; ++ch)
      vv[ch] = ok ? qkv[bb + (size_t)(128 + chg[ch]) * HWP + sp] : 0.f;
    float4* vrow = (float4*)(vr + tt * KVP);
    vrow[0] = make_float4(vv[0],  vv[1],  vv[2],  vv[3]);
    vrow[1] = make_float4(vv[4],  vv[5],  vv[6],  vv[7]);
    vrow[2] = make_float4(vv[8],  vv[9],  vv[10], vv[11]);
    vrow[3] = make_float4(vv[12], vv[13], vv[14], vv[15]);
  }
  // ---- per-query q (overlaps staging latency) ----
  int qy = hi * 8 + (t >> 3), qx = wj * 8 + (t & 7);
  float q[16];
  float qs = 0.f;
#pragma unroll
  for (int ch = 0; ch < 16; ++ch) {
    q[ch] = qkv[bb + (size_t)chg[ch] * HWP + qy * 128 + qx];
    qs += q[ch] * q[ch];
  }
  float T = expf(temp[head]);
  float qnT = T / fmaxf(sqrtf(qs), 1e-12f);
  __syncthreads();
  // ---- 50 keys per wave, all operands from LDS broadcasts ----
  float out[16];
#pragma unroll
  for (int ch = 0; ch < 16; ++ch) out[ch] = 0.f;
  float wsum = 0.f;
  for (int pyl = 0; pyl < 5; ++pyl) {
    int py = w * 5 + pyl;
    const float* kp0 = kr + py * 10 * KVP;
    const float* vp0 = vr + py * 10 * KVP;
    for (int px = 0; px < 10; ++px) {
      const float* kp = kp0 + px * KVP;
      const float* vp = vp0 + px * KVP;
      float d0 = 0.f, d1 = 0.f, d2 = 0.f, d3 = 0.f;
#pragma unroll
      for (int ch = 0; ch < 4; ++ch) {
        d0 = fmaf(q[ch], kp[ch], d0);
        d1 = fmaf(q[ch + 4], kp[ch + 4], d1);
        d2 = fmaf(q[ch + 8], kp[ch + 8], d2);
        d3 = fmaf(q[ch + 12], kp[ch + 12], d3);
      }
      float dacc = (d0 + d1) + (d2 + d3);
      float e = __expf(fmaf(dacc, qnT, -T));      // exp(d - T): exact softmax shift
      wsum += e;                                  // OOB keys count in denominator
#pragma unroll
      for (int ch = 0; ch < 16; ++ch)
        out[ch] = fmaf(e, vp[ch], out[ch]);       // OOB rows are zero -> no mask
    }
  }
  // ---- cross-wave combine: po/pw overlay the dead kr region ----
  __syncthreads();                 // both waves done reading kr/vr
  float* po = smem;                // [2][16][64] = 2048 floats
  float* pwp = smem + 2048;        // [2][64] -> ends 2176 < 4000
  pwp[w * 64 + t] = wsum;
#pragma unroll
  for (int ch = 0; ch < 16; ++ch) po[(w * 16 + ch) * 64 + t] = out[ch];
  __syncthreads();
  float winv = 1.f / (pwp[t] + pwp[64 + t]);
  int ob = w * 8;                                 // this wave's 8 outputs
#pragma unroll
  for (int i = 0; i < 8; ++i) {
    int o = ob + i;
    float oc = po[o * 64 + t] + po[(16 + o) * 64 + t];
    float gsv = gate_b[head * 16 + o];
#pragma unroll
    for (int c = 0; c < 16; ++c)
      gsv = fmaf(gate_w[head * 256 + o * 16 + c], q[c], gsv);
    float sig = 1.f / (1.f + __expf(-gsv));
    attn_out[((size_t)b * 64 + chg[o]) * HWP + qy * 128 + qx] = oc * winv * sig;
  }
}

// ---------------- 8: mixed -> gating -> down -> up -> (+attn) -> proj ----
// attn lives in its own buffer: channel c of batch b at (b*64+c)*HWP.
// 256 threads = 4 waves per block, 64 pixels per block (lane = pixel).
// Output channels are SPLIT ACROSS WAVES (16/wave; 8/wave for down).
// Per-channel accumulator chain order (d ascending) unchanged -> bitwise-
// identical results.
__global__ __launch_bounds__(256) void k_post(
    const float* __restrict__ attn, const float* __restrict__ qkv,
    const float* __restrict__ gT, const float* __restrict__ gating_b,
    const float* __restrict__ dT, const float* __restrict__ down_b,
    const float* __restrict__ uT, const float* __restrict__ up_b,
    const float* __restrict__ pT, float* __restrict__ out3) {
  __shared__ float xs[64 * 64];     // [c][pix]
  int t = threadIdx.x;
  int lane = t & 63;                // pixel within block
  int w = t >> 6;                   // wave 0..3 (uniform)
  int p = blockIdx.x * 64 + lane;   // global pooled pixel id
  int b = p >> 14;
  int pix = p & 16383;
  const float* ap = attn + (size_t)b * 64 * HWP + pix;
  const float* qp = qkv + (size_t)b * 192 * HWP + pix;
  float* op = out3 + (size_t)b * 64 * HWP + pix;
  int ob16 = __builtin_amdgcn_readfirstlane(w * 16);
  int ob8  = __builtin_amdgcn_readfirstlane(w * 8);
  // mixed = attn_out + (q + k): each wave loads its 16 channels (concurrent)
#pragma unroll
  for (int i = 0; i < 16; ++i) {
    int c = ob16 + i;
    xs[c * 64 + lane] = ap[(size_t)c * HWP] + qp[(size_t)c * HWP] + qp[(size_t)(64 + c) * HWP];
  }
  __syncthreads();
  // ---- gating conv + exact gelu, * mixed ----
  {
    float acc[16];
#pragma unroll
    for (int o = 0; o < 16; ++o) acc[o] = gating_b[ob16 + o];
    for (int d = 0; d < 64; ++d) {
      float xv = xs[d * 64 + lane];
      const float* wd = gT + d * 64 + ob16;   // wave-uniform -> s_load
#pragma unroll
      for (int o = 0; o < 16; ++o) acc[o] = fmaf(wd[o], xv, acc[o]);
    }
    __syncthreads();                 // all reads done before any overwrite
#pragma unroll
    for (int o = 0; o < 16; ++o) {
      float a = acc[o];
      float ge = 0.5f * a * (1.f + erff(a * 0.70710678118654752f));
      xs[(ob16 + o) * 64 + lane] = ge * xs[(ob16 + o) * 64 + lane];
    }
    __syncthreads();
  }
  // ---- down 64->32 (8 outputs/wave) ----
  {
    float acc[8];
#pragma unroll
    for (int o = 0; o < 8; ++o) acc[o] = down_b[ob8 + o];
    for (int d = 0; d < 64; ++d) {
      float xv = xs[d * 64 + lane];
      const float* wd = dT + d * 32 + ob8;
#pragma unroll
      for (int o = 0; o < 8; ++o) acc[o] = fmaf(wd[o], xv, acc[o]);
    }
    __syncthreads();
#pragma unroll
    for (int o = 0; o < 8; ++o) xs[(ob8 + o) * 64 + lane] = acc[o];
    __syncthreads();
  }
  // ---- up 32->64, + attn residual ----
  {
    float acc[16];
#pragma unroll
    for (int o = 0; o < 16; ++o) acc[o] = up_b[ob16 + o];
    for (int d = 0; d < 32; ++d) {
      float xv = xs[d * 64 + lane];
      const float* wd = uT + d * 64 + ob16;
#pragma unroll
      for (int o = 0; o < 16; ++o) acc[o] = fmaf(wd[o], xv, acc[o]);
    }
    __syncthreads();
#pragma unroll
    for (int o = 0; o < 16; ++o)
      xs[(ob16 + o) * 64 + lane] = acc[o] + ap[(size_t)(ob16 + o) * HWP];
    __syncthreads();
  }
  // ---- proj (no bias) ----
  {
    float acc[16];
#pragma unroll
    for (int o = 0; o < 16; ++o) acc[o] = 0.f;
    for (int d = 0; d < 64; ++d) {
      float xv = xs[d * 64 + lane];
      const float* wd = pT + d * 64 + ob16;
#pragma unroll
      for (int o = 0; o < 16; ++o) acc[o] = fmaf(wd[o], xv, acc[o]);
    }
#pragma unroll
    for (int o = 0; o < 16; ++o) op[(size_t)(ob16 + o) * HWP] = acc[o];
  }
}

// ---------------- 9: dw3x3 reflect + bias + bilinear x2 (align-corners) ----
__global__ __launch_bounds__(256) void k_final(
    const float* __restrict__ out3, const float* __restrict__ lp_w,
    const float* __restrict__ lp_b, float* __restrict__ out) {
  int bi = blockIdx.x;                 // (b*64+ch)*8 + rt
  int rt = bi & 7;
  int bc = bi >> 3;
  int ch = bc & 63;
  int r0 = rt * 16;
  __shared__ float tin[20 * 128];      // input rows r0-2 .. r0+17 (reflected)
  __shared__ float tdw[18 * 128];      // dw rows r0-1 .. r0+16
  int t = threadIdx.x;
  const float* src = out3 + (size_t)bc * HWP;
  for (int i = 0; i < 10; ++i) {
    int f = i * 256 + t;               // 2560 exactly
    int r = f >> 7, xx = f & 127;
    int ry = r0 - 2 + r;
    ry = ry < 0 ? -ry : (ry > 127 ? 254 - ry : ry);
    tin[f] = src[ry * 128 + xx];
  }
  __syncthreads();
  float w0 = lp_w[ch * 9 + 0], w1 = lp_w[ch * 9 + 1], w2 = lp_w[ch * 9 + 2];
  float w3 = lp_w[ch * 9 + 3], w4 = lp_w[ch * 9 + 4], w5 = lp_w[ch * 9 + 5];
  float w6 = lp_w[ch * 9 + 6], w7 = lp_w[ch * 9 + 7], w8 = lp_w[ch * 9 + 8];
  float bias = lp_b[ch];
  for (int i = 0; i < 9; ++i) {
    int f = i * 256 + t;               // 2304 exactly
    int r = f >> 7, xx = f & 127;
    int xm = (xx == 0) ? 1 : xx - 1;
    int xp = (xx == 127) ? 126 : xx + 1;
    const float* r0p = tin + r * 128;
    const float* r1p = r0p + 128;
    const float* r2p = r1p + 128;
    float acc = bias;
    acc = fmaf(w0, r0p[xm], acc); acc = fmaf(w1, r0p[xx], acc); acc = fmaf(w2, r0p[xp], acc);
    acc = fmaf(w3, r1p[xm], acc); acc = fmaf(w4, r1p[xx], acc); acc = fmaf(w5, r1p[xp], acc);
    acc = fmaf(w6, r2p[xm], acc); acc = fmaf(w7, r2p[xx], acc); acc = fmaf(w8, r2p[xp], acc);
    tdw[f] = acc;
  }
  __syncthreads();
  const float s = (float)(127.0 / 255.0);
  float* dst = out + (size_t)bc * 65536;
  for (int i = 0; i < 32; ++i) {
    int f = i * 256 + t;               // 8192 exactly: rows 2r0..2r0+31, cols 0..255
    int vr = f >> 8, vx = f & 255;
    int v = 2 * r0 + vr;
    float cy = (float)v * s;
    int ly = (int)floorf(cy); if (ly > 126) ly = 126;
    float wy = cy - (float)ly;
    float cx = (float)vx * s;
    int lx = (int)floorf(cx); if (lx > 126) lx = 126;
    float wx = cx - (float)lx;
    int lr = ly - r0 + 1;              // tdw row index
    float a  = tdw[lr * 128 + lx];
    float bq = tdw[lr * 128 + lx + 1];
    float c2 = tdw[(lr + 1) * 128 + lx];
    float d2 = tdw[(lr + 1) * 128 + lx + 1];
    float t0 = a  * (1.f - wy) + c2 * wy;   // y-lerp first (matches ref order)
    float t1 = bq * (1.f - wy) + d2 * wy;
    dst[v * 256 + vx] = t0 * (1.f - wx) + t1 * wx;
  }
}

extern "C" void kernel_launch(void* const* d_in, const int* in_sizes, int n_in,
                              void* d_out, int out_size, void* d_ws, size_t ws_size,
                              hipStream_t stream) {
  (void)in_sizes; (void)n_in; (void)out_size; (void)ws_size;
  const float* x        = (const float*)d_in[0];
  const float* qkv_w    = (const float*)d_in[1];
  const float* lce_w    = (const float*)d_in[2];
  const float* gate_w   = (const float*)d_in[3];
  const float* gate_b   = (const float*)d_in[4];
  const float* temp     = (const float*)d_in[5];
  const float* rel_h    = (const float*)d_in[6];
  const float* rel_w    = (const float*)d_in[7];
  const float* down_w   = (const float*)d_in[8];
  const float* down_b   = (const float*)d_in[9];
  const float* up_w     = (const float*)d_in[10];
  const float* up_b     = (const float*)d_in[11];
  const float* gating_w = (const float*)d_in[12];
  const float* gating_b = (const float*)d_in[13];
  const float* proj_w   = (const float*)d_in[14];
  const float* lp_w     = (const float*)d_in[15];
  const float* lp_b     = (const float*)d_in[16];
  float* fws = (float*)d_ws;
  float* outp = (float*)d_out;

  float* pre  = fws + PRE_OFF;
  float* qkv  = fws + QKV_OFF;
  float* attn = fws + ATTN_OFF;
  float* out3 = fws + OUT3_OFF;
  float* covp = fws + COVP_OFF;
  float* mean = fws + MEAN_OFF;
  int* idx = (int*)(fws + IDX_OFF);
  int* inv = (int*)(fws + INV_OFF);
  float* covs = fws + COVS_OFF;
  float* wT   = fws + WT_OFF;
  float* gT   = fws + GT2_OFF;
  float* dT   = fws + DT2_OFF;
  float* uT   = fws + UT2_OFF;
  float* pT   = fws + PT2_OFF;

  k_prep_wt<<<48, 256, 0, stream>>>(qkv_w, wT);
  k_pool_conv<<<1024, 256, 0, stream>>>(x, wT, pre);
  k_dw3x3_zero<<<12288, 256, 0, stream>>>(pre, lce_w, qkv);
  k_prep2<<<16, 256, 0, stream>>>(gating_w, down_w, up_w, proj_w, gT, dT, uT, pT);
  k_mean<<<256, 256, 0, stream>>>(qkv, mean);
  k_covpart<<<512, 256, 0, stream>>>(qkv, mean, covp);
  k_covred<<<64, 256, 0, stream>>>(covp, covs);
  k_simsort<<<4, 256, 0, stream>>>(covs, idx, inv);
  k_attn<<<4096, 128, 0, stream>>>(qkv, idx, rel_h, rel_w, gate_w, gate_b, temp, attn);
  k_post<<<1024, 256, 0, stream>>>(attn, qkv, gT, gating_b, dT, down_b,
                                   uT, up_b, pT, out3);
  k_final<<<2048, 256, 0, stream>>>(out3, lp_w, lp_b, outp);
  (void)inv;
}

// Round 12
// 362.610 us; speedup vs baseline: 1.0564x; 1.0428x over previous
//
#include <hip/hip_runtime.h>
#include <math.h>

#define HWP 16384   // 128*128 pooled plane

// ---------------- workspace layout (float offsets) ----------------
// Lifetimes (same-stream serialization):
//   pre   [0, 12,582,912)          pool_conv -> dw3x3
//   cov   [0, ~2.12M)              mean -> simsort      (inside dead pre)
//   attn  [0, 4,194,304)           attn -> post         (inside dead pre)
//   out3  [4,194,304, 8,388,608)   post -> final        (inside dead pre)
//   tail  [12,570,112, 12,582,912) idx/inv + MLP weights, written only
//                                  after dw3x3, live through post
//   qkv   [12,582,912, 25,165,824) dw3x3 -> post; READ-ONLY after dw3x3
static const size_t PRE_OFF  = 0;          // 12,582,912
static const size_t QKV_OFF  = 12582912;
// wT lives at the START of the QKV region: written by k_prep_wt, read only by
// k_pool_conv (which writes PRE only), then overwritten by k_dw3x3_zero.
static const size_t WT_OFF   = QKV_OFF;    // 12,288 floats
static const size_t COVP_OFF = 0;          // 2,097,152
static const size_t MEAN_OFF = 2097152;    // 256
static const size_t COVS_OFF = 2097408;    // 16,384 -> ends 2,113,792
static const size_t ATTN_OFF = 0;          // 4,194,304 (cov dead by attn)
static const size_t OUT3_OFF = 4194304;    // 4,194,304 -> ends 8,388,608
static const size_t IDX_OFF  = 12570112;   // 256 ints
static const size_t INV_OFF  = 12570368;   // 256 ints
static const size_t GT2_OFF  = 12570624;   // 4096
static const size_t DT2_OFF  = 12574720;   // 2048
static const size_t UT2_OFF  = 12576768;   // 2048
static const size_t PT2_OFF  = 12578816;   // 4096 -> ends 12,582,912 exactly

// ---------------- 0: transpose qkv_w -> wT[c*192+o] ----------------
__global__ __launch_bounds__(256) void k_prep_wt(
    const float* __restrict__ qkv_w, float* __restrict__ wT) {
  int i = blockIdx.x * 256 + threadIdx.x;   // 12288
  int o = i >> 6, c = i & 63;
  wT[c * 192 + o] = qkv_w[i];
}

// ---------------- 0b: transpose MLP weights to d-major ----------------
__global__ __launch_bounds__(256) void k_prep2(
    const float* __restrict__ gating_w, const float* __restrict__ down_w,
    const float* __restrict__ up_w, const float* __restrict__ proj_w,
    float* __restrict__ gT, float* __restrict__ dT,
    float* __restrict__ uT, float* __restrict__ pT) {
  int t = blockIdx.x * 256 + threadIdx.x;
  if (t < 4096) {
    int o = t >> 6, d = t & 63;
    gT[d * 64 + o] = gating_w[t];
    pT[d * 64 + o] = proj_w[t];
  }
  if (t < 2048) {
    int o = t >> 6, d = t & 63;      // down_w (32,64)
    dT[d * 32 + o] = down_w[t];
    int o2 = t >> 5, d2 = t & 31;    // up_w (64,32)
    uT[d2 * 64 + o2] = up_w[t];
  }
}

// ---------------- 1: maxpool2 + conv1x1 (x -> qkv_pre) ----------------
// x loads float4 (each thread pools TWO adjacent output pixels from two 16B
// row segments); fmax tree per pixel unchanged -> bitwise-identical pre.
__global__ __launch_bounds__(256) void k_pool_conv(
    const float* __restrict__ x, const float* __restrict__ wT,
    float* __restrict__ pre) {
  int b = blockIdx.x >> 8;          // 256 tiles / batch
  int pix0 = (blockIdx.x & 255) * 64;
  __shared__ float xt[64 * 64];     // [c][p]
  int t = threadIdx.x;
  for (int i = 0; i < 8; ++i) {
    int f = i * 256 + t;            // 2048 = 64c * 32 pixel-pairs
    int c = f >> 5, pp = (f & 31) * 2;
    int pix = pix0 + pp;            // pix0 is 64-aligned -> pair in one row
    int y = pix >> 7, xx = pix & 127;   // xx even -> 2*xx*4B is 16B-aligned
    const float* src = x + ((size_t)(b * 64 + c) * 65536) + (2 * y) * 256 + 2 * xx;
    float4 r0 = *(const float4*)src;
    float4 r1 = *(const float4*)(src + 256);
    xt[c * 64 + pp]     = fmaxf(fmaxf(r0.x, r0.y), fmaxf(r1.x, r1.y));
    xt[c * 64 + pp + 1] = fmaxf(fmaxf(r0.z, r0.w), fmaxf(r1.z, r1.w));
  }
  __syncthreads();
  int p = t & 63;
  int obase = __builtin_amdgcn_readfirstlane((t >> 6) * 48);  // wave-uniform
  const float* wbase = wT + obase;
  float acc[48];
#pragma unroll
  for (int j = 0; j < 48; ++j) acc[j] = 0.f;
  for (int c = 0; c < 64; ++c) {
    float xv = xt[c * 64 + p];
    const float* wc = wbase + c * 192;    // uniform -> s_load_dwordx16 x3
#pragma unroll
    for (int j = 0; j < 48; ++j) acc[j] = fmaf(wc[j], xv, acc[j]);
  }
  float* dst = pre + ((size_t)b * 192 + obase) * HWP + pix0 + p;
#pragma unroll
  for (int j = 0; j < 48; ++j) dst[(size_t)j * HWP] = acc[j];
}

// ---------------- 2: depthwise 3x3, zero pad (pre -> qkv) ----------------
// float4 per thread (4 pixels); boundary zeros fed through the SAME fmaf
// chain order as scalar skip logic -> bitwise-identical output.
__global__ __launch_bounds__(256) void k_dw3x3_zero(
    const float* __restrict__ pre, const float* __restrict__ lce_w,
    float* __restrict__ qkv) {
  int gid = blockIdx.x * 256 + threadIdx.x;   // over 768*128*32 float4s
  int c4 = gid & 31;
  int y  = (gid >> 5) & 127;
  int bc = gid >> 12;                          // b*192 + ch
  int ch = bc % 192;
  int x0 = c4 * 4;
  const float* base = pre + (size_t)bc * HWP;
  const float* w = lce_w + ch * 9;
  const float4 z4 = make_float4(0.f, 0.f, 0.f, 0.f);
  bool ym = y > 0, yp = y < 127;
  bool xl = x0 > 0, xr = x0 < 124;
  const float* rowm = base + (y - 1) * 128;
  const float* rowc = base + y * 128;
  const float* rowp = base + (y + 1) * 128;
  float4 vm = ym ? *(const float4*)(rowm + x0) : z4;
  float  lm = (ym && xl) ? rowm[x0 - 1] : 0.f;
  float  rm = (ym && xr) ? rowm[x0 + 4] : 0.f;
  float4 vc = *(const float4*)(rowc + x0);
  float  lc = xl ? rowc[x0 - 1] : 0.f;
  float  rc = xr ? rowc[x0 + 4] : 0.f;
  float4 vp = yp ? *(const float4*)(rowp + x0) : z4;
  float  lp = (yp && xl) ? rowp[x0 - 1] : 0.f;
  float  rp = (yp && xr) ? rowp[x0 + 4] : 0.f;
  float w0 = w[0], w1 = w[1], w2 = w[2], w3 = w[3], w4 = w[4],
        w5 = w[5], w6 = w[6], w7 = w[7], w8 = w[8];
  float4 o;
  o.x = fmaf(w8, vp.y, fmaf(w7, vp.x, fmaf(w6, lp,
        fmaf(w5, vc.y, fmaf(w4, vc.x, fmaf(w3, lc,
        fmaf(w2, vm.y, fmaf(w1, vm.x, fmaf(w0, lm, 0.f)))))))));
  o.y = fmaf(w8, vp.z, fmaf(w7, vp.y, fmaf(w6, vp.x,
        fmaf(w5, vc.z, fmaf(w4, vc.y, fmaf(w3, vc.x,
        fmaf(w2, vm.z, fmaf(w1, vm.y, fmaf(w0, vm.x, 0.f)))))))));
  o.z = fmaf(w8, vp.w, fmaf(w7, vp.z, fmaf(w6, vp.y,
        fmaf(w5, vc.w, fmaf(w4, vc.z, fmaf(w3, vc.y,
        fmaf(w2, vm.w, fmaf(w1, vm.z, fmaf(w0, vm.y, 0.f)))))))));
  o.w = fmaf(w8, rp,   fmaf(w7, vp.w, fmaf(w6, vp.z,
        fmaf(w5, rc,   fmaf(w4, vc.w, fmaf(w3, vc.z,
        fmaf(w2, rm,   fmaf(w1, vm.w, fmaf(w0, vm.z, 0.f)))))))));
  *(float4*)(qkv + (size_t)bc * HWP + y * 128 + x0) = o;
}

// ---------------- 3a: per-channel mean of q ----------------
__global__ __launch_bounds__(256) void k_mean(
    const float* __restrict__ qkv, float* __restrict__ mean) {
  int bc = blockIdx.x;              // b*64 + c
  int b = bc >> 6, c = bc & 63;
  const float* src = qkv + ((size_t)b * 192 + c) * HWP;
  float s = 0.f;
  for (int i = threadIdx.x; i < HWP; i += 256) s += src[i];
  __shared__ float red[4];
  for (int off = 32; off > 0; off >>= 1) s += __shfl_down(s, off);
  int t = threadIdx.x;
  if ((t & 63) == 0) red[t >> 6] = s;
  __syncthreads();
  if (t == 0) mean[bc] = (red[0] + red[1] + red[2] + red[3]) * (1.f / 16384.f);
}

// ---------------- 3b: centered cov partials (chunks of 128) ----------------
__global__ __launch_bounds__(256) void k_covpart(
    const float* __restrict__ qkv, const float* __restrict__ mean,
    float* __restrict__ covp) {
  int blk = blockIdx.x;             // b*128 + chunk
  int b = blk >> 7, chunk = blk & 127;
  int e0 = chunk * 128;
  __shared__ float qc[64 * 129];    // +1 pad breaks stride conflicts
  int t = threadIdx.x;
  for (int i = 0; i < 32; ++i) {
    int f = i * 256 + t;
    int c = f >> 7, e = f & 127;
    qc[c * 129 + e] = qkv[((size_t)b * 192 + c) * HWP + e0 + e] - mean[b * 64 + c];
  }
  __syncthreads();
  int d = t & 63;
  int crow = t >> 6;                // wave-uniform
  float acc[16];
#pragma unroll
  for (int i = 0; i < 16; ++i) acc[i] = 0.f;
  for (int e = 0; e < 128; ++e) {
    float qd = qc[d * 129 + e];
#pragma unroll
    for (int i = 0; i < 16; ++i) {
      int c = crow + 4 * i;
      acc[i] = fmaf(qc[c * 129 + e], qd, acc[i]);
    }
  }
  float* dst = covp + (size_t)blk * 4096;
#pragma unroll
  for (int i = 0; i < 16; ++i) {
    int c = crow + 4 * i;
    dst[c * 64 + d] = acc[i];       // == dst[i*256 + t], coalesced
  }
}

// ---------------- 3b2: reduce cov partials over 128 chunks ----------------
__global__ __launch_bounds__(256) void k_covred(
    const float* __restrict__ covp, float* __restrict__ covs) {
  int blk = blockIdx.x;             // b*16 + j
  int b = blk >> 4;
  int pp = (blk & 15) * 256 + threadIdx.x;
  const float* src = covp + (size_t)b * 524288 + pp;
  float s = 0.f;
  for (int ch = 0; ch < 128; ++ch) s += src[ch * 4096];   // chunk order preserved
  covs[b * 4096 + pp] = s;
}

// ---------------- 3c: correlation-mean sim, stable rank ----------------
__global__ __launch_bounds__(256) void k_simsort(
    const float* __restrict__ covs_g, int* __restrict__ idx, int* __restrict__ inv) {
  int b = blockIdx.x;               // 4 blocks
  __shared__ float covs[4096];
  __shared__ float stds[64];
  __shared__ float sims[64];
  int t = threadIdx.x;
  for (int i = 0; i < 16; ++i) covs[i * 256 + t] = covs_g[b * 4096 + i * 256 + t];
  __syncthreads();
  if (t < 64) stds[t] = sqrtf(covs[t * 64 + t] + 1e-8f);
  __syncthreads();
  if (t < 64) {
    float s = 0.f;
    float sc = stds[t];
    for (int d2 = 0; d2 < 64; ++d2) {
      float denom = fmaxf(sc * stds[d2], 1e-8f);
      s += covs[d2 * 64 + t] / denom;   // symmetric matrix: bitwise equal to [t][d2]
    }
    sims[t] = s * (1.f / 64.f);
  }
  __syncthreads();
  if (t < 64) {
    float sv = sims[t];
    int r = 0;
    for (int d2 = 0; d2 < 64; ++d2) {
      float o = sims[d2];
      if (o > sv || (o == sv && d2 < t)) r++;
    }
    idx[b * 64 + r] = t;
    inv[b * 64 + t] = r;
  }
}

// ---------------- 7: FUSED stage + halo block attention + gate ----------
// Round-9 2-wave version (proven 55.4us, conflicts 0). r10 showed per-wave
// fixed work (q-gather) scales with wave count -> 2 waves is the optimum;
// VALU-busy 32us == the fp32 VALU floor (no fp32 MFMA on CDNA4).
#define KVP 20   // padded row stride: 80B, gcd(20,32)=4 -> 8 bank groups
__global__ __launch_bounds__(128) void k_attn(
    const float* __restrict__ qkv, const int* __restrict__ idx,
    const float* __restrict__ rel_h, const float* __restrict__ rel_w,
    const float* __restrict__ gate_w, const float* __restrict__ gate_b,
    const float* __restrict__ temp, float* __restrict__ attn_out) {
  int bi = blockIdx.x;
  int head = bi & 3;
  int wj = (bi >> 2) & 15;
  int hi = (bi >> 6) & 15;
  int b = bi >> 10;
  int tt = threadIdx.x;                            // 0..127
  int t = tt & 63;                                 // lane = query
  int w = __builtin_amdgcn_readfirstlane(tt >> 6); // wave 0/1
  __shared__ __align__(16) float smem[2 * 100 * KVP];  // kr | vr, 16000 B
  float* kr = smem;
  float* vr = smem + 100 * KVP;
  const size_t bb = (size_t)b * 192 * HWP;
  int chg[16];
#pragma unroll
  for (int ch = 0; ch < 16; ++ch) chg[ch] = idx[b * 64 + head * 16 + ch];
  // ---- fused staging: one halo position per thread ----
  if (tt < 100) {
    int py = tt / 10, px = tt - py * 10;
    int ky = hi * 8 + py - 1, kx = wj * 8 + px - 1;
    bool ok = (ky >= 0) && (ky < 128) && (kx >= 0) && (kx < 128);
    int sp = ky * 128 + kx;
    float kv[16];
    float s = 0.f;
#pragma unroll
    for (int ch = 0; ch < 16; ++ch) {
      float k = ok ? qkv[bb + (size_t)(64 + chg[ch]) * HWP + sp] : 0.f;
      k += (ch < 8) ? rel_h[(head * 10 + py) * 8 + ch]
                    : rel_w[(head * 10 + px) * 8 + (ch - 8)];
      kv[ch] = k;
      s += k * k;
    }
    float rn = 1.f / fmaxf(sqrtf(s), 1e-12f);     // ref: l2norm(k+rel) pre-dot
    float4* krow = (float4*)(kr + tt * KVP);
    krow[0] = make_float4(kv[0] * rn,  kv[1] * rn,  kv[2] * rn,  kv[3] * rn);
    krow[1] = make_float4(kv[4] * rn,  kv[5] * rn,  kv[6] * rn,  kv[7] * rn);
    krow[2] = make_float4(kv[8] * rn,  kv[9] * rn,  kv[10] * rn, kv[11] * rn);
    krow[3] = make_float4(kv[12] * rn, kv[13] * rn, kv[14] * rn, kv[15] * rn);
    float vv[16];
#pragma unroll
    for (int ch = 0; ch < 16; ++ch)
      vv[ch] = ok ? qkv[bb + (size_t)(128 + chg[ch]) * HWP + sp] : 0.f;
    float4* vrow = (float4*)(vr + tt * KVP);
    vrow[0] = make_float4(vv[0],  vv[1],  vv[2],  vv[3]);
    vrow[1] = make_float4(vv[4],  vv[5],  vv[6],  vv[7]);
    vrow[2] = make_float4(vv[8],  vv[9],  vv[10], vv[11]);
    vrow[3] = make_float4(vv[12], vv[13], vv[14], vv[15]);
  }
  // ---- per-query q (overlaps staging latency) ----
  int qy = hi * 8 + (t >> 3), qx = wj * 8 + (t & 7);
  float q[16];
  float qs = 0.f;
#pragma unroll
  for (int ch = 0; ch < 16; ++ch) {
    q[ch] = qkv[bb + (size_t)chg[ch] * HWP + qy * 128 + qx];
    qs += q[ch] * q[ch];
  }
  float T = expf(temp[head]);
  float qnT = T / fmaxf(sqrtf(qs), 1e-12f);
  __syncthreads();
  // ---- 50 keys per wave, all operands from LDS broadcasts ----
  float out[16];
#pragma unroll
  for (int ch = 0; ch < 16; ++ch) out[ch] = 0.f;
  float wsum = 0.f;
  for (int pyl = 0; pyl < 5; ++pyl) {
    int py = w * 5 + pyl;
    const float* kp0 = kr + py * 10 * KVP;
    const float* vp0 = vr + py * 10 * KVP;
    for (int px = 0; px < 10; ++px) {
      const float* kp = kp0 + px * KVP;
      const float* vp = vp0 + px * KVP;
      float d0 = 0.f, d1 = 0.f, d2 = 0.f, d3 = 0.f;
#pragma unroll
      for (int ch = 0; ch < 4; ++ch) {
        d0 = fmaf(q[ch], kp[ch], d0);
        d1 = fmaf(q[ch + 4], kp[ch + 4], d1);
        d2 = fmaf(q[ch + 8], kp[ch + 8], d2);
        d3 = fmaf(q[ch + 12], kp[ch + 12], d3);
      }
      float dacc = (d0 + d1) + (d2 + d3);
      float e = __expf(fmaf(dacc, qnT, -T));      // exp(d - T): exact softmax shift
      wsum += e;                                  // OOB keys count in denominator
#pragma unroll
      for (int ch = 0; ch < 16; ++ch)
        out[ch] = fmaf(e, vp[ch], out[ch]);       // OOB rows are zero -> no mask
    }
  }
  // ---- cross-wave combine: po/pw overlay the dead kr region ----
  __syncthreads();                 // both waves done reading kr/vr
  float* po = smem;                // [2][16][64] = 2048 floats
  float* pwp = smem + 2048;        // [2][64] -> ends 2176 < 4000
  pwp[w * 64 + t] = wsum;
#pragma unroll
  for (int ch = 0; ch < 16; ++ch) po[(w * 16 + ch) * 64 + t] = out[ch];
  __syncthreads();
  float winv = 1.f / (pwp[t] + pwp[64 + t]);
  int ob = w * 8;                                 // this wave's 8 outputs
#pragma unroll
  for (int i = 0; i < 8; ++i) {
    int o = ob + i;
    float oc = po[o * 64 + t] + po[(16 + o) * 64 + t];
    float gsv = gate_b[head * 16 + o];
#pragma unroll
    for (int c = 0; c < 16; ++c)
      gsv = fmaf(gate_w[head * 256 + o * 16 + c], q[c], gsv);
    float sig = 1.f / (1.f + __expf(-gsv));
    attn_out[((size_t)b * 64 + chg[o]) * HWP + qy * 128 + qx] = oc * winv * sig;
  }
}

// ---------------- 8: mixed -> gating -> down -> up -> (+attn) -> proj ----
// attn lives in its own buffer: channel c of batch b at (b*64+c)*HWP.
// 256 threads = 4 waves per block, 64 pixels per block (lane = pixel).
// Output channels are SPLIT ACROSS WAVES (16/wave; 8/wave for down).
__global__ __launch_bounds__(256) void k_post(
    const float* __restrict__ attn, const float* __restrict__ qkv,
    const float* __restrict__ gT, const float* __restrict__ gating_b,
    const float* __restrict__ dT, const float* __restrict__ down_b,
    const float* __restrict__ uT, const float* __restrict__ up_b,
    const float* __restrict__ pT, float* __restrict__ out3) {
  __shared__ float xs[64 * 64];     // [c][pix]
  int t = threadIdx.x;
  int lane = t & 63;                // pixel within block
  int w = t >> 6;                   // wave 0..3 (uniform)
  int p = blockIdx.x * 64 + lane;   // global pooled pixel id
  int b = p >> 14;
  int pix = p & 16383;
  const float* ap = attn + (size_t)b * 64 * HWP + pix;
  const float* qp = qkv + (size_t)b * 192 * HWP + pix;
  float* op = out3 + (size_t)b * 64 * HWP + pix;
  int ob16 = __builtin_amdgcn_readfirstlane(w * 16);
  int ob8  = __builtin_amdgcn_readfirstlane(w * 8);
  // mixed = attn_out + (q + k): each wave loads its 16 channels (concurrent)
#pragma unroll
  for (int i = 0; i < 16; ++i) {
    int c = ob16 + i;
    xs[c * 64 + lane] = ap[(size_t)c * HWP] + qp[(size_t)c * HWP] + qp[(size_t)(64 + c) * HWP];
  }
  __syncthreads();
  // ---- gating conv + exact gelu, * mixed ----
  {
    float acc[16];
#pragma unroll
    for (int o = 0; o < 16; ++o) acc[o] = gating_b[ob16 + o];
    for (int d = 0; d < 64; ++d) {
      float xv = xs[d * 64 + lane];
      const float* wd = gT + d * 64 + ob16;   // wave-uniform -> s_load
#pragma unroll
      for (int o = 0; o < 16; ++o) acc[o] = fmaf(wd[o], xv, acc[o]);
    }
    __syncthreads();                 // all reads done before any overwrite
#pragma unroll
    for (int o = 0; o < 16; ++o) {
      float a = acc[o];
      float ge = 0.5f * a * (1.f + erff(a * 0.70710678118654752f));
      xs[(ob16 + o) * 64 + lane] = ge * xs[(ob16 + o) * 64 + lane];
    }
    __syncthreads();
  }
  // ---- down 64->32 (8 outputs/wave) ----
  {
    float acc[8];
#pragma unroll
    for (int o = 0; o < 8; ++o) acc[o] = down_b[ob8 + o];
    for (int d = 0; d < 64; ++d) {
      float xv = xs[d * 64 + lane];
      const float* wd = dT + d * 32 + ob8;
#pragma unroll
      for (int o = 0; o < 8; ++o) acc[o] = fmaf(wd[o], xv, acc[o]);
    }
    __syncthreads();
#pragma unroll
    for (int o = 0; o < 8; ++o) xs[(ob8 + o) * 64 + lane] = acc[o];
    __syncthreads();
  }
  // ---- up 32->64, + attn residual ----
  {
    float acc[16];
#pragma unroll
    for (int o = 0; o < 16; ++o) acc[o] = up_b[ob16 + o];
    for (int d = 0; d < 32; ++d) {
      float xv = xs[d * 64 + lane];
      const float* wd = uT + d * 64 + ob16;
#pragma unroll
      for (int o = 0; o < 16; ++o) acc[o] = fmaf(wd[o], xv, acc[o]);
    }
    __syncthreads();
#pragma unroll
    for (int o = 0; o < 16; ++o)
      xs[(ob16 + o) * 64 + lane] = acc[o] + ap[(size_t)(ob16 + o) * HWP];
    __syncthreads();
  }
  // ---- proj (no bias) ----
  {
    float acc[16];
#pragma unroll
    for (int o = 0; o < 16; ++o) acc[o] = 0.f;
    for (int d = 0; d < 64; ++d) {
      float xv = xs[d * 64 + lane];
      const float* wd = pT + d * 64 + ob16;
#pragma unroll
      for (int o = 0; o < 16; ++o) acc[o] = fmaf(wd[o], xv, acc[o]);
    }
#pragma unroll
    for (int o = 0; o < 16; ++o) op[(size_t)(ob16 + o) * HWP] = acc[o];
  }
}

// ---------------- 9: dw3x3 reflect + bias + bilinear x2 (align-corners) ----
// Round-12: vectorized VMEM. tin loads float4 (2560 -> 640 load instrs;
// reflection remaps rows only, columns stay contiguous). Bilinear output:
// each thread computes 4 consecutive vx and stores ONE dwordx4 (8192 -> 2048
// store instrs). Per-element lerp arithmetic and order unchanged ->
// bitwise-identical output. This kernel writes 67MB as scalar stores before
// -- the same VMEM-issue-bound signature dw3x3 had at 70.7us pre-float4.
__global__ __launch_bounds__(256) void k_final(
    const float* __restrict__ out3, const float* __restrict__ lp_w,
    const float* __restrict__ lp_b, float* __restrict__ out) {
  int bi = blockIdx.x;                 // (b*64+ch)*8 + rt
  int rt = bi & 7;
  int bc = bi >> 3;
  int ch = bc & 63;
  int r0 = rt * 16;
  __shared__ __align__(16) float tin[20 * 128];  // rows r0-2 .. r0+17 (reflected)
  __shared__ __align__(16) float tdw[18 * 128];  // dw rows r0-1 .. r0+16
  int t = threadIdx.x;
  const float* src = out3 + (size_t)bc * HWP;
  for (int i = 0; i < 3; ++i) {
    int f = i * 256 + t;               // 640 float4s (20 rows x 32)
    if (f < 640) {
      int r = f >> 5, x4 = (f & 31) * 4;
      int ry = r0 - 2 + r;
      ry = ry < 0 ? -ry : (ry > 127 ? 254 - ry : ry);
      *(float4*)(tin + r * 128 + x4) = *(const float4*)(src + ry * 128 + x4);
    }
  }
  __syncthreads();
  float w0 = lp_w[ch * 9 + 0], w1 = lp_w[ch * 9 + 1], w2 = lp_w[ch * 9 + 2];
  float w3 = lp_w[ch * 9 + 3], w4 = lp_w[ch * 9 + 4], w5 = lp_w[ch * 9 + 5];
  float w6 = lp_w[ch * 9 + 6], w7 = lp_w[ch * 9 + 7], w8 = lp_w[ch * 9 + 8];
  float bias = lp_b[ch];
  for (int i = 0; i < 9; ++i) {
    int f = i * 256 + t;               // 2304 exactly
    int r = f >> 7, xx = f & 127;
    int xm = (xx == 0) ? 1 : xx - 1;
    int xp = (xx == 127) ? 126 : xx + 1;
    const float* r0p = tin + r * 128;
    const float* r1p = r0p + 128;
    const float* r2p = r1p + 128;
    float acc = bias;
    acc = fmaf(w0, r0p[xm], acc); acc = fmaf(w1, r0p[xx], acc); acc = fmaf(w2, r0p[xp], acc);
    acc = fmaf(w3, r1p[xm], acc); acc = fmaf(w4, r1p[xx], acc); acc = fmaf(w5, r1p[xp], acc);
    acc = fmaf(w6, r2p[xm], acc); acc = fmaf(w7, r2p[xx], acc); acc = fmaf(w8, r2p[xp], acc);
    tdw[f] = acc;
  }
  __syncthreads();
  const float s = (float)(127.0 / 255.0);
  float* dst = out + (size_t)bc * 65536;
  for (int i = 0; i < 8; ++i) {
    int f = i * 256 + t;               // 2048 float4s: rows 2r0..2r0+31, 64 f4/row
    int vr = f >> 6, vx4 = (f & 63) * 4;
    int v = 2 * r0 + vr;
    float cy = (float)v * s;
    int ly = (int)floorf(cy); if (ly > 126) ly = 126;
    float wy = cy - (float)ly;
    int lr = ly - r0 + 1;              // tdw row index (same for all 4 vx)
    const float* trow0 = tdw + lr * 128;
    const float* trow1 = trow0 + 128;
    float4 ov;
#pragma unroll
    for (int j = 0; j < 4; ++j) {
      int vx = vx4 + j;
      float cx = (float)vx * s;
      int lx = (int)floorf(cx); if (lx > 126) lx = 126;
      float wx = cx - (float)lx;
      float a  = trow0[lx];
      float bq = trow0[lx + 1];
      float c2 = trow1[lx];
      float d2 = trow1[lx + 1];
      float t0 = a  * (1.f - wy) + c2 * wy;   // y-lerp first (matches ref order)
      float t1 = bq * (1.f - wy) + d2 * wy;
      (&ov.x)[j] = t0 * (1.f - wx) + t1 * wx;
    }
    *(float4*)(dst + v * 256 + vx4) = ov;
  }
}

extern "C" void kernel_launch(void* const* d_in, const int* in_sizes, int n_in,
                              void* d_out, int out_size, void* d_ws, size_t ws_size,
                              hipStream_t stream) {
  (void)in_sizes; (void)n_in; (void)out_size; (void)ws_size;
  const float* x        = (const float*)d_in[0];
  const float* qkv_w    = (const float*)d_in[1];
  const float* lce_w    = (const float*)d_in[2];
  const float* gate_w   = (const float*)d_in[3];
  const float* gate_b   = (const float*)d_in[4];
  const float* temp     = (const float*)d_in[5];
  const float* rel_h    = (const float*)d_in[6];
  const float* rel_w    = (const float*)d_in[7];
  const float* down_w   = (const float*)d_in[8];
  const float* down_b   = (const float*)d_in[9];
  const float* up_w     = (const float*)d_in[10];
  const float* up_b     = (const float*)d_in[11];
  const float* gating_w = (const float*)d_in[12];
  const float* gating_b = (const float*)d_in[13];
  const float* proj_w   = (const float*)d_in[14];
  const float* lp_w     = (const float*)d_in[15];
  const float* lp_b     = (const float*)d_in[16];
  float* fws = (float*)d_ws;
  float* outp = (float*)d_out;

  float* pre  = fws + PRE_OFF;
  float* qkv  = fws + QKV_OFF;
  float* attn = fws + ATTN_OFF;
  float* out3 = fws + OUT3_OFF;
  float* covp = fws + COVP_OFF;
  float* mean = fws + MEAN_OFF;
  int* idx = (int*)(fws + IDX_OFF);
  int* inv = (int*)(fws + INV_OFF);
  float* covs = fws + COVS_OFF;
  float* wT   = fws + WT_OFF;
  float* gT   = fws + GT2_OFF;
  float* dT   = fws + DT2_OFF;
  float* uT   = fws + UT2_OFF;
  float* pT   = fws + PT2_OFF;

  k_prep_wt<<<48, 256, 0, stream>>>(qkv_w, wT);
  k_pool_conv<<<1024, 256, 0, stream>>>(x, wT, pre);
  k_dw3x3_zero<<<12288, 256, 0, stream>>>(pre, lce_w, qkv);
  k_prep2<<<16, 256, 0, stream>>>(gating_w, down_w, up_w, proj_w, gT, dT, uT, pT);
  k_mean<<<256, 256, 0, stream>>>(qkv, mean);
  k_covpart<<<512, 256, 0, stream>>>(qkv, mean, covp);
  k_covred<<<64, 256, 0, stream>>>(covp, covs);
  k_simsort<<<4, 256, 0, stream>>>(covs, idx, inv);
  k_attn<<<4096, 128, 0, stream>>>(qkv, idx, rel_h, rel_w, gate_w, gate_b, temp, attn);
  k_post<<<1024, 256, 0, stream>>>(attn, qkv, gT, gating_b, dT, down_b,
                                   uT, up_b, pT, out3);
  k_final<<<2048, 256, 0, stream>>>(out3, lp_w, lp_b, outp);
  (void)inv;
}

// Round 14
// 359.844 us; speedup vs baseline: 1.0646x; 1.0077x over previous
//
#include <hip/hip_runtime.h>
#include <math.h>

#define HWP 16384   // 128*128 pooled plane

typedef float f32x2 __attribute__((ext_vector_type(2)));
typedef float f32x4 __attribute__((ext_vector_type(4)));

// v_pk_fma_f32: packed dual FP32 FMA on VGPR pairs (CDNA1+). Per-component
// IEEE fma -> bitwise identical to scalar fmaf per element.
static __device__ __forceinline__ f32x2 pk_fma(f32x2 a, f32x2 b, f32x2 c) {
  f32x2 d;
  asm("v_pk_fma_f32 %0, %1, %2, %3" : "=v"(d) : "v"(a), "v"(b), "v"(c));
  return d;
}

// ---------------- workspace layout (float offsets) ----------------
// Lifetimes (same-stream serialization):
//   pre   [0, 12,582,912)          pool_conv -> dw3x3
//   cov   [0, ~2.12M)              mean -> simsort      (inside dead pre)
//   attn  [0, 4,194,304)           attn -> post         (inside dead pre)
//   out3  [4,194,304, 8,388,608)   post -> final        (inside dead pre)
//   tail  [12,570,112, 12,582,912) idx/inv + MLP weights, written only
//                                  after dw3x3, live through post
//   qkv   [12,582,912, 25,165,824) dw3x3 -> post; READ-ONLY after dw3x3
static const size_t PRE_OFF  = 0;          // 12,582,912
static const size_t QKV_OFF  = 12582912;
// wT lives at the START of the QKV region: written by k_prep_wt, read only by
// k_pool_conv (which writes PRE only), then overwritten by k_dw3x3_zero.
static const size_t WT_OFF   = QKV_OFF;    // 12,288 floats
static const size_t COVP_OFF = 0;          // 2,097,152
static const size_t MEAN_OFF = 2097152;    // 256
static const size_t COVS_OFF = 2097408;    // 16,384 -> ends 2,113,792
static const size_t ATTN_OFF = 0;          // 4,194,304 (cov dead by attn)
static const size_t OUT3_OFF = 4194304;    // 4,194,304 -> ends 8,388,608
static const size_t IDX_OFF  = 12570112;   // 256 ints
static const size_t INV_OFF  = 12570368;   // 256 ints
static const size_t GT2_OFF  = 12570624;   // 4096
static const size_t DT2_OFF  = 12574720;   // 2048
static const size_t UT2_OFF  = 12576768;   // 2048
static const size_t PT2_OFF  = 12578816;   // 4096 -> ends 12,582,912 exactly

// ---------------- 0: transpose qkv_w -> wT[c*192+o] ----------------
__global__ __launch_bounds__(256) void k_prep_wt(
    const float* __restrict__ qkv_w, float* __restrict__ wT) {
  int i = blockIdx.x * 256 + threadIdx.x;   // 12288
  int o = i >> 6, c = i & 63;
  wT[c * 192 + o] = qkv_w[i];
}

// ---------------- 0b: transpose MLP weights to d-major ----------------
__global__ __launch_bounds__(256) void k_prep2(
    const float* __restrict__ gating_w, const float* __restrict__ down_w,
    const float* __restrict__ up_w, const float* __restrict__ proj_w,
    float* __restrict__ gT, float* __restrict__ dT,
    float* __restrict__ uT, float* __restrict__ pT) {
  int t = blockIdx.x * 256 + threadIdx.x;
  if (t < 4096) {
    int o = t >> 6, d = t & 63;
    gT[d * 64 + o] = gating_w[t];
    pT[d * 64 + o] = proj_w[t];
  }
  if (t < 2048) {
    int o = t >> 6, d = t & 63;      // down_w (32,64)
    dT[d * 32 + o] = down_w[t];
    int o2 = t >> 5, d2 = t & 31;    // up_w (64,32)
    uT[d2 * 64 + o2] = up_w[t];
  }
}

// ---------------- 1: maxpool2 + conv1x1 (x -> qkv_pre) ----------------
// x loads float4 (each thread pools TWO adjacent output pixels from two 16B
// row segments); fmax tree per pixel unchanged -> bitwise-identical pre.
__global__ __launch_bounds__(256) void k_pool_conv(
    const float* __restrict__ x, const float* __restrict__ wT,
    float* __restrict__ pre) {
  int b = blockIdx.x >> 8;          // 256 tiles / batch
  int pix0 = (blockIdx.x & 255) * 64;
  __shared__ float xt[64 * 64];     // [c][p]
  int t = threadIdx.x;
  for (int i = 0; i < 8; ++i) {
    int f = i * 256 + t;            // 2048 = 64c * 32 pixel-pairs
    int c = f >> 5, pp = (f & 31) * 2;
    int pix = pix0 + pp;            // pix0 is 64-aligned -> pair in one row
    int y = pix >> 7, xx = pix & 127;   // xx even -> 2*xx*4B is 16B-aligned
    const float* src = x + ((size_t)(b * 64 + c) * 65536) + (2 * y) * 256 + 2 * xx;
    float4 r0 = *(const float4*)src;
    float4 r1 = *(const float4*)(src + 256);
    xt[c * 64 + pp]     = fmaxf(fmaxf(r0.x, r0.y), fmaxf(r1.x, r1.y));
    xt[c * 64 + pp + 1] = fmaxf(fmaxf(r0.z, r0.w), fmaxf(r1.z, r1.w));
  }
  __syncthreads();
  int p = t & 63;
  int obase = __builtin_amdgcn_readfirstlane((t >> 6) * 48);  // wave-uniform
  const float* wbase = wT + obase;
  float acc[48];
#pragma unroll
  for (int j = 0; j < 48; ++j) acc[j] = 0.f;
  for (int c = 0; c < 64; ++c) {
    float xv = xt[c * 64 + p];
    const float* wc = wbase + c * 192;    // uniform -> s_load_dwordx16 x3
#pragma unroll
    for (int j = 0; j < 48; ++j) acc[j] = fmaf(wc[j], xv, acc[j]);
  }
  float* dst = pre + ((size_t)b * 192 + obase) * HWP + pix0 + p;
#pragma unroll
  for (int j = 0; j < 48; ++j) dst[(size_t)j * HWP] = acc[j];
}

// ---------------- 2: depthwise 3x3, zero pad (pre -> qkv) ----------------
// float4 per thread (4 pixels); boundary zeros fed through the SAME fmaf
// chain order as scalar skip logic -> bitwise-identical output.
__global__ __launch_bounds__(256) void k_dw3x3_zero(
    const float* __restrict__ pre, const float* __restrict__ lce_w,
    float* __restrict__ qkv) {
  int gid = blockIdx.x * 256 + threadIdx.x;   // over 768*128*32 float4s
  int c4 = gid & 31;
  int y  = (gid >> 5) & 127;
  int bc = gid >> 12;                          // b*192 + ch
  int ch = bc % 192;
  int x0 = c4 * 4;
  const float* base = pre + (size_t)bc * HWP;
  const float* w = lce_w + ch * 9;
  const float4 z4 = make_float4(0.f, 0.f, 0.f, 0.f);
  bool ym = y > 0, yp = y < 127;
  bool xl = x0 > 0, xr = x0 < 124;
  const float* rowm = base + (y - 1) * 128;
  const float* rowc = base + y * 128;
  const float* rowp = base + (y + 1) * 128;
  float4 vm = ym ? *(const float4*)(rowm + x0) : z4;
  float  lm = (ym && xl) ? rowm[x0 - 1] : 0.f;
  float  rm = (ym && xr) ? rowm[x0 + 4] : 0.f;
  float4 vc = *(const float4*)(rowc + x0);
  float  lc = xl ? rowc[x0 - 1] : 0.f;
  float  rc = xr ? rowc[x0 + 4] : 0.f;
  float4 vp = yp ? *(const float4*)(rowp + x0) : z4;
  float  lp = (yp && xl) ? rowp[x0 - 1] : 0.f;
  float  rp = (yp && xr) ? rowp[x0 + 4] : 0.f;
  float w0 = w[0], w1 = w[1], w2 = w[2], w3 = w[3], w4 = w[4],
        w5 = w[5], w6 = w[6], w7 = w[7], w8 = w[8];
  float4 o;
  o.x = fmaf(w8, vp.y, fmaf(w7, vp.x, fmaf(w6, lp,
        fmaf(w5, vc.y, fmaf(w4, vc.x, fmaf(w3, lc,
        fmaf(w2, vm.y, fmaf(w1, vm.x, fmaf(w0, lm, 0.f)))))))));
  o.y = fmaf(w8, vp.z, fmaf(w7, vp.y, fmaf(w6, vp.x,
        fmaf(w5, vc.z, fmaf(w4, vc.y, fmaf(w3, vc.x,
        fmaf(w2, vm.z, fmaf(w1, vm.y, fmaf(w0, vm.x, 0.f)))))))));
  o.z = fmaf(w8, vp.w, fmaf(w7, vp.z, fmaf(w6, vp.y,
        fmaf(w5, vc.w, fmaf(w4, vc.z, fmaf(w3, vc.y,
        fmaf(w2, vm.w, fmaf(w1, vm.z, fmaf(w0, vm.y, 0.f)))))))));
  o.w = fmaf(w8, rp,   fmaf(w7, vp.w, fmaf(w6, vp.z,
        fmaf(w5, rc,   fmaf(w4, vc.w, fmaf(w3, vc.z,
        fmaf(w2, rm,   fmaf(w1, vm.w, fmaf(w0, vm.z, 0.f)))))))));
  *(float4*)(qkv + (size_t)bc * HWP + y * 128 + x0) = o;
}

// ---------------- 3a: per-channel mean of q ----------------
__global__ __launch_bounds__(256) void k_mean(
    const float* __restrict__ qkv, float* __restrict__ mean) {
  int bc = blockIdx.x;              // b*64 + c
  int b = bc >> 6, c = bc & 63;
  const float* src = qkv + ((size_t)b * 192 + c) * HWP;
  float s = 0.f;
  for (int i = threadIdx.x; i < HWP; i += 256) s += src[i];
  __shared__ float red[4];
  for (int off = 32; off > 0; off >>= 1) s += __shfl_down(s, off);
  int t = threadIdx.x;
  if ((t & 63) == 0) red[t >> 6] = s;
  __syncthreads();
  if (t == 0) mean[bc] = (red[0] + red[1] + red[2] + red[3]) * (1.f / 16384.f);
}

// ---------------- 3b: centered cov partials (chunks of 128) ----------------
__global__ __launch_bounds__(256) void k_covpart(
    const float* __restrict__ qkv, const float* __restrict__ mean,
    float* __restrict__ covp) {
  int blk = blockIdx.x;             // b*128 + chunk
  int b = blk >> 7, chunk = blk & 127;
  int e0 = chunk * 128;
  __shared__ float qc[64 * 129];    // +1 pad breaks stride conflicts
  int t = threadIdx.x;
  for (int i = 0; i < 32; ++i) {
    int f = i * 256 + t;
    int c = f >> 7, e = f & 127;
    qc[c * 129 + e] = qkv[((size_t)b * 192 + c) * HWP + e0 + e] - mean[b * 64 + c];
  }
  __syncthreads();
  int d = t & 63;
  int crow = t >> 6;                // wave-uniform
  float acc[16];
#pragma unroll
  for (int i = 0; i < 16; ++i) acc[i] = 0.f;
  for (int e = 0; e < 128; ++e) {
    float qd = qc[d * 129 + e];
#pragma unroll
    for (int i = 0; i < 16; ++i) {
      int c = crow + 4 * i;
      acc[i] = fmaf(qc[c * 129 + e], qd, acc[i]);
    }
  }
  float* dst = covp + (size_t)blk * 4096;
#pragma unroll
  for (int i = 0; i < 16; ++i) {
    int c = crow + 4 * i;
    dst[c * 64 + d] = acc[i];       // == dst[i*256 + t], coalesced
  }
}

// ---------------- 3b2: reduce cov partials over 128 chunks ----------------
__global__ __launch_bounds__(256) void k_covred(
    const float* __restrict__ covp, float* __restrict__ covs) {
  int blk = blockIdx.x;             // b*16 + j
  int b = blk >> 4;
  int pp = (blk & 15) * 256 + threadIdx.x;
  const float* src = covp + (size_t)b * 524288 + pp;
  float s = 0.f;
  for (int ch = 0; ch < 128; ++ch) s += src[ch * 4096];   // chunk order preserved
  covs[b * 4096 + pp] = s;
}

// ---------------- 3c: correlation-mean sim, stable rank ----------------
__global__ __launch_bounds__(256) void k_simsort(
    const float* __restrict__ covs_g, int* __restrict__ idx, int* __restrict__ inv) {
  int b = blockIdx.x;               // 4 blocks
  __shared__ float covs[4096];
  __shared__ float stds[64];
  __shared__ float sims[64];
  int t = threadIdx.x;
  for (int i = 0; i < 16; ++i) covs[i * 256 + t] = covs_g[b * 4096 + i * 256 + t];
  __syncthreads();
  if (t < 64) stds[t] = sqrtf(covs[t * 64 + t] + 1e-8f);
  __syncthreads();
  if (t < 64) {
    float s = 0.f;
    float sc = stds[t];
    for (int d2 = 0; d2 < 64; ++d2) {
      float denom = fmaxf(sc * stds[d2], 1e-8f);
      s += covs[d2 * 64 + t] / denom;   // symmetric matrix: bitwise equal to [t][d2]
    }
    sims[t] = s * (1.f / 64.f);
  }
  __syncthreads();
  if (t < 64) {
    float sv = sims[t];
    int r = 0;
    for (int d2 = 0; d2 < 64; ++d2) {
      float o = sims[d2];
      if (o > sv || (o == sv && d2 < t)) r++;
    }
    idx[b * 64 + r] = t;
    inv[b * 64 + t] = r;
  }
}

// ---------------- 7: FUSED stage + halo block attention + gate ----------
// Packed fp32 inner loop. r9/r12 busy-time (32us) matches the SCALAR
// issue-count model (~39 VALU/key) -> compiler is not packing. The 16-wide
// dot and 16-wide V-accumulate are v_pk_fma_f32 on f32x2 lanes (8 pk ops
// each): ~25 issues/key, -35% VALU floor. out[ch] chains keep the same
// per-element fma order -> bitwise identical; dot reduction is a
// reassociation (same class as r4/r5/r9 splits). LDS reads stay 4x
// ds_read_b128 per operand (f32x4 loads, .xy/.zw swizzles = even-aligned
// pairs). Gate/staging stay scalar (SGPR operands free in scalar FMA).
#define KVP 20   // padded row stride: 80B, gcd(20,32)=4 -> 8 bank groups
__global__ __launch_bounds__(128) void k_attn(
    const float* __restrict__ qkv, const int* __restrict__ idx,
    const float* __restrict__ rel_h, const float* __restrict__ rel_w,
    const float* __restrict__ gate_w, const float* __restrict__ gate_b,
    const float* __restrict__ temp, float* __restrict__ attn_out) {
  int bi = blockIdx.x;
  int head = bi & 3;
  int wj = (bi >> 2) & 15;
  int hi = (bi >> 6) & 15;
  int b = bi >> 10;
  int tt = threadIdx.x;                            // 0..127
  int t = tt & 63;                                 // lane = query
  int w = __builtin_amdgcn_readfirstlane(tt >> 6); // wave 0/1
  __shared__ __align__(16) float smem[2 * 100 * KVP];  // kr | vr, 16000 B
  float* kr = smem;
  float* vr = smem + 100 * KVP;
  const size_t bb = (size_t)b * 192 * HWP;
  int chg[16];
#pragma unroll
  for (int ch = 0; ch < 16; ++ch) chg[ch] = idx[b * 64 + head * 16 + ch];
  // ---- fused staging: one halo position per thread ----
  if (tt < 100) {
    int py = tt / 10, px = tt - py * 10;
    int ky = hi * 8 + py - 1, kx = wj * 8 + px - 1;
    bool ok = (ky >= 0) && (ky < 128) && (kx >= 0) && (kx < 128);
    int sp = ky * 128 + kx;
    float kv[16];
    float s = 0.f;
#pragma unroll
    for (int ch = 0; ch < 16; ++ch) {
      float k = ok ? qkv[bb + (size_t)(64 + chg[ch]) * HWP + sp] : 0.f;
      k += (ch < 8) ? rel_h[(head * 10 + py) * 8 + ch]
                    : rel_w[(head * 10 + px) * 8 + (ch - 8)];
      kv[ch] = k;
      s += k * k;
    }
    float rn = 1.f / fmaxf(sqrtf(s), 1e-12f);     // ref: l2norm(k+rel) pre-dot
    float4* krow = (float4*)(kr + tt * KVP);
    krow[0] = make_float4(kv[0] * rn,  kv[1] * rn,  kv[2] * rn,  kv[3] * rn);
    krow[1] = make_float4(kv[4] * rn,  kv[5] * rn,  kv[6] * rn,  kv[7] * rn);
    krow[2] = make_float4(kv[8] * rn,  kv[9] * rn,  kv[10] * rn, kv[11] * rn);
    krow[3] = make_float4(kv[12] * rn, kv[13] * rn, kv[14] * rn, kv[15] * rn);
    float vv[16];
#pragma unroll
    for (int ch = 0; ch < 16; ++ch)
      vv[ch] = ok ? qkv[bb + (size_t)(128 + chg[ch]) * HWP + sp] : 0.f;
    float4* vrow = (float4*)(vr + tt * KVP);
    vrow[0] = make_float4(vv[0],  vv[1],  vv[2],  vv[3]);
    vrow[1] = make_float4(vv[4],  vv[5],  vv[6],  vv[7]);
    vrow[2] = make_float4(vv[8],  vv[9],  vv[10], vv[11]);
    vrow[3] = make_float4(vv[12], vv[13], vv[14], vv[15]);
  }
  // ---- per-query q (overlaps staging latency) ----
  int qy = hi * 8 + (t >> 3), qx = wj * 8 + (t & 7);
  float q[16];
  float qs = 0.f;
#pragma unroll
  for (int ch = 0; ch < 16; ++ch) {
    q[ch] = qkv[bb + (size_t)chg[ch] * HWP + qy * 128 + qx];
    qs += q[ch] * q[ch];
  }
  float T = expf(temp[head]);
  float qnT = T / fmaxf(sqrtf(qs), 1e-12f);
  f32x2 q2[8];
#pragma unroll
  for (int j = 0; j < 8; ++j) { q2[j].x = q[2 * j]; q2[j].y = q[2 * j + 1]; }
  __syncthreads();
  // ---- 50 keys per wave, packed fp32 math, LDS broadcast operands ----
  const f32x2 zz = {0.f, 0.f};
  f32x2 o2[8];
#pragma unroll
  for (int j = 0; j < 8; ++j) o2[j] = zz;
  float wsum = 0.f;
  for (int pyl = 0; pyl < 5; ++pyl) {
    int py = w * 5 + pyl;
    const float* kp0 = kr + py * 10 * KVP;
    const float* vp0 = vr + py * 10 * KVP;
    for (int px = 0; px < 10; ++px) {
      const f32x4* kp4 = (const f32x4*)(kp0 + px * KVP);
      const f32x4* vp4 = (const f32x4*)(vp0 + px * KVP);
      f32x4 kA = kp4[0], kB = kp4[1], kC = kp4[2], kD = kp4[3];
      f32x4 vA = vp4[0], vB = vp4[1], vC = vp4[2], vD = vp4[3];
      f32x2 dd0 = q2[0] * kA.xy;              // v_pk_mul_f32
      f32x2 dd1 = q2[1] * kA.zw;
      f32x2 dd2 = q2[2] * kB.xy;
      f32x2 dd3 = q2[3] * kB.zw;
      dd0 = pk_fma(q2[4], kC.xy, dd0);
      dd1 = pk_fma(q2[5], kC.zw, dd1);
      dd2 = pk_fma(q2[6], kD.xy, dd2);
      dd3 = pk_fma(q2[7], kD.zw, dd3);
      f32x2 dsA = dd0 + dd1;                  // v_pk_add_f32
      f32x2 dsB = dd2 + dd3;
      f32x2 dsC = dsA + dsB;
      float dacc = dsC.x + dsC.y;
      float e = __expf(fmaf(dacc, qnT, -T));  // exp(d - T): exact softmax shift
      wsum += e;                              // OOB keys count in denominator
      f32x2 e2; e2.x = e; e2.y = e;
      o2[0] = pk_fma(e2, vA.xy, o2[0]);       // per-element fma, same key
      o2[1] = pk_fma(e2, vA.zw, o2[1]);       // order as scalar -> bitwise
      o2[2] = pk_fma(e2, vB.xy, o2[2]);       // identical out[ch]
      o2[3] = pk_fma(e2, vB.zw, o2[3]);
      o2[4] = pk_fma(e2, vC.xy, o2[4]);
      o2[5] = pk_fma(e2, vC.zw, o2[5]);
      o2[6] = pk_fma(e2, vD.xy, o2[6]);
      o2[7] = pk_fma(e2, vD.zw, o2[7]);
    }
  }
  // ---- cross-wave combine: po/pw overlay the dead kr region ----
  __syncthreads();                 // both waves done reading kr/vr
  float* po = smem;                // [2][16][64] = 2048 floats
  float* pwp = smem + 2048;        // [2][64] -> ends 2176 < 4000
  pwp[w * 64 + t] = wsum;
#pragma unroll
  for (int j = 0; j < 8; ++j) {
    po[(w * 16 + 2 * j) * 64 + t]     = o2[j].x;
    po[(w * 16 + 2 * j + 1) * 64 + t] = o2[j].y;
  }
  __syncthreads();
  float winv = 1.f / (pwp[t] + pwp[64 + t]);
  int ob = w * 8;                                 // this wave's 8 outputs
#pragma unroll
  for (int i = 0; i < 8; ++i) {
    int o = ob + i;
    float oc = po[o * 64 + t] + po[(16 + o) * 64 + t];
    float gsv = gate_b[head * 16 + o];
#pragma unroll
    for (int c = 0; c < 16; ++c)
      gsv = fmaf(gate_w[head * 256 + o * 16 + c], q[c], gsv);
    float sig = 1.f / (1.f + __expf(-gsv));
    attn_out[((size_t)b * 64 + chg[o]) * HWP + qy * 128 + qx] = oc * winv * sig;
  }
}

// ---------------- 8: mixed -> gating -> down -> up -> (+attn) -> proj ----
// attn lives in its own buffer: channel c of batch b at (b*64+c)*HWP.
// 256 threads = 4 waves per block, 64 pixels per block (lane = pixel).
// Output channels are SPLIT ACROSS WAVES (16/wave; 8/wave for down).
__global__ __launch_bounds__(256) void k_post(
    const float* __restrict__ attn, const float* __restrict__ qkv,
    const float* __restrict__ gT, const float* __restrict__ gating_b,
    const float* __restrict__ dT, const float* __restrict__ down_b,
    const float* __restrict__ uT, const float* __restrict__ up_b,
    const float* __restrict__ pT, float* __restrict__ out3) {
  __shared__ float xs[64 * 64];     // [c][pix]
  int t = threadIdx.x;
  int lane = t & 63;                // pixel within block
  int w = t >> 6;                   // wave 0..3 (uniform)
  int p = blockIdx.x * 64 + lane;   // global pooled pixel id
  int b = p >> 14;
  int pix = p & 16383;
  const float* ap = attn + (size_t)b * 64 * HWP + pix;
  const float* qp = qkv + (size_t)b * 192 * HWP + pix;
  float* op = out3 + (size_t)b * 64 * HWP + pix;
  int ob16 = __builtin_amdgcn_readfirstlane(w * 16);
  int ob8  = __builtin_amdgcn_readfirstlane(w * 8);
  // mixed = attn_out + (q + k): each wave loads its 16 channels (concurrent)
#pragma unroll
  for (int i = 0; i < 16; ++i) {
    int c = ob16 + i;
    xs[c * 64 + lane] = ap[(size_t)c * HWP] + qp[(size_t)c * HWP] + qp[(size_t)(64 + c) * HWP];
  }
  __syncthreads();
  // ---- gating conv + exact gelu, * mixed ----
  {
    float acc[16];
#pragma unroll
    for (int o = 0; o < 16; ++o) acc[o] = gating_b[ob16 + o];
    for (int d = 0; d < 64; ++d) {
      float xv = xs[d * 64 + lane];
      const float* wd = gT + d * 64 + ob16;   // wave-uniform -> s_load
#pragma unroll
      for (int o = 0; o < 16; ++o) acc[o] = fmaf(wd[o], xv, acc[o]);
    }
    __syncthreads();                 // all reads done before any overwrite
#pragma unroll
    for (int o = 0; o < 16; ++o) {
      float a = acc[o];
      float ge = 0.5f * a * (1.f + erff(a * 0.70710678118654752f));
      xs[(ob16 + o) * 64 + lane] = ge * xs[(ob16 + o) * 64 + lane];
    }
    __syncthreads();
  }
  // ---- down 64->32 (8 outputs/wave) ----
  {
    float acc[8];
#pragma unroll
    for (int o = 0; o < 8; ++o) acc[o] = down_b[ob8 + o];
    for (int d = 0; d < 64; ++d) {
      float xv = xs[d * 64 + lane];
      const float* wd = dT + d * 32 + ob8;
#pragma unroll
      for (int o = 0; o < 8; ++o) acc[o] = fmaf(wd[o], xv, acc[o]);
    }
    __syncthreads();
#pragma unroll
    for (int o = 0; o < 8; ++o) xs[(ob8 + o) * 64 + lane] = acc[o];
    __syncthreads();
  }
  // ---- up 32->64, + attn residual ----
  {
    float acc[16];
#pragma unroll
    for (int o = 0; o < 16; ++o) acc[o] = up_b[ob16 + o];
    for (int d = 0; d < 32; ++d) {
      float xv = xs[d * 64 + lane];
      const float* wd = uT + d * 64 + ob16;
#pragma unroll
      for (int o = 0; o < 16; ++o) acc[o] = fmaf(wd[o], xv, acc[o]);
    }
    __syncthreads();
#pragma unroll
    for (int o = 0; o < 16; ++o)
      xs[(ob16 + o) * 64 + lane] = acc[o] + ap[(size_t)(ob16 + o) * HWP];
    __syncthreads();
  }
  // ---- proj (no bias) ----
  {
    float acc[16];
#pragma unroll
    for (int o = 0; o < 16; ++o) acc[o] = 0.f;
    for (int d = 0; d < 64; ++d) {
      float xv = xs[d * 64 + lane];
      const float* wd = pT + d * 64 + ob16;
#pragma unroll
      for (int o = 0; o < 16; ++o) acc[o] = fmaf(wd[o], xv, acc[o]);
    }
#pragma unroll
    for (int o = 0; o < 16; ++o) op[(size_t)(ob16 + o) * HWP] = acc[o];
  }
}

// ---------------- 9: dw3x3 reflect + bias + bilinear x2 (align-corners) ----
// Vectorized VMEM: tin float4 loads (640 instrs), output one dwordx4 per
// 4 consecutive vx (2048 stores). Lerp arithmetic/order unchanged ->
// bitwise-identical output.
__global__ __launch_bounds__(256) void k_final(
    const float* __restrict__ out3, const float* __restrict__ lp_w,
    const float* __restrict__ lp_b, float* __restrict__ out) {
  int bi = blockIdx.x;                 // (b*64+ch)*8 + rt
  int rt = bi & 7;
  int bc = bi >> 3;
  int ch = bc & 63;
  int r0 = rt * 16;
  __shared__ __align__(16) float tin[20 * 128];  // rows r0-2 .. r0+17 (reflected)
  __shared__ __align__(16) float tdw[18 * 128];  // dw rows r0-1 .. r0+16
  int t = threadIdx.x;
  const float* src = out3 + (size_t)bc * HWP;
  for (int i = 0; i < 3; ++i) {
    int f = i * 256 + t;               // 640 float4s (20 rows x 32)
    if (f < 640) {
      int r = f >> 5, x4 = (f & 31) * 4;
      int ry = r0 - 2 + r;
      ry = ry < 0 ? -ry : (ry > 127 ? 254 - ry : ry);
      *(float4*)(tin + r * 128 + x4) = *(const float4*)(src + ry * 128 + x4);
    }
  }
  __syncthreads();
  float w0 = lp_w[ch * 9 + 0], w1 = lp_w[ch * 9 + 1], w2 = lp_w[ch * 9 + 2];
  float w3 = lp_w[ch * 9 + 3], w4 = lp_w[ch * 9 + 4], w5 = lp_w[ch * 9 + 5];
  float w6 = lp_w[ch * 9 + 6], w7 = lp_w[ch * 9 + 7], w8 = lp_w[ch * 9 + 8];
  float bias = lp_b[ch];
  for (int i = 0; i < 9; ++i) {
    int f = i * 256 + t;               // 2304 exactly
    int r = f >> 7, xx = f & 127;
    int xm = (xx == 0) ? 1 : xx - 1;
    int xp = (xx == 127) ? 126 : xx + 1;
    const float* r0p = tin + r * 128;
    const float* r1p = r0p + 128;
    const float* r2p = r1p + 128;
    float acc = bias;
    acc = fmaf(w0, r0p[xm], acc); acc = fmaf(w1, r0p[xx], acc); acc = fmaf(w2, r0p[xp], acc);
    acc = fmaf(w3, r1p[xm], acc); acc = fmaf(w4, r1p[xx], acc); acc = fmaf(w5, r1p[xp], acc);
    acc = fmaf(w6, r2p[xm], acc); acc = fmaf(w7, r2p[xx], acc); acc = fmaf(w8, r2p[xp], acc);
    tdw[f] = acc;
  }
  __syncthreads();
  const float s = (float)(127.0 / 255.0);
  float* dst = out + (size_t)bc * 65536;
  for (int i = 0; i < 8; ++i) {
    int f = i * 256 + t;               // 2048 float4s: rows 2r0..2r0+31, 64 f4/row
    int vr = f >> 6, vx4 = (f & 63) * 4;
    int v = 2 * r0 + vr;
    float cy = (float)v * s;
    int ly = (int)floorf(cy); if (ly > 126) ly = 126;
    float wy = cy - (float)ly;
    int lr = ly - r0 + 1;              // tdw row index (same for all 4 vx)
    const float* trow0 = tdw + lr * 128;
    const float* trow1 = trow0 + 128;
    float4 ov;
#pragma unroll
    for (int j = 0; j < 4; ++j) {
      int vx = vx4 + j;
      float cx = (float)vx * s;
      int lx = (int)floorf(cx); if (lx > 126) lx = 126;
      float wx = cx - (float)lx;
      float a  = trow0[lx];
      float bq = trow0[lx + 1];
      float c2 = trow1[lx];
      float d2 = trow1[lx + 1];
      float t0 = a  * (1.f - wy) + c2 * wy;   // y-lerp first (matches ref order)
      float t1 = bq * (1.f - wy) + d2 * wy;
      (&ov.x)[j] = t0 * (1.f - wx) + t1 * wx;
    }
    *(float4*)(dst + v * 256 + vx4) = ov;
  }
}

extern "C" void kernel_launch(void* const* d_in, const int* in_sizes, int n_in,
                              void* d_out, int out_size, void* d_ws, size_t ws_size,
                              hipStream_t stream) {
  (void)in_sizes; (void)n_in; (void)out_size; (void)ws_size;
  const float* x        = (const float*)d_in[0];
  const float* qkv_w    = (const float*)d_in[1];
  const float* lce_w    = (const float*)d_in[2];
  const float* gate_w   = (const float*)d_in[3];
  const float* gate_b   = (const float*)d_in[4];
  const float* temp     = (const float*)d_in[5];
  const float* rel_h    = (const float*)d_in[6];
  const float* rel_w    = (const float*)d_in[7];
  const float* down_w   = (const float*)d_in[8];
  const float* down_b   = (const float*)d_in[9];
  const float* up_w     = (const float*)d_in[10];
  const float* up_b     = (const float*)d_in[11];
  const float* gating_w = (const float*)d_in[12];
  const float* gating_b = (const float*)d_in[13];
  const float* proj_w   = (const float*)d_in[14];
  const float* lp_w     = (const float*)d_in[15];
  const float* lp_b     = (const float*)d_in[16];
  float* fws = (float*)d_ws;
  float* outp = (float*)d_out;

  float* pre  = fws + PRE_OFF;
  float* qkv  = fws + QKV_OFF;
  float* attn = fws + ATTN_OFF;
  float* out3 = fws + OUT3_OFF;
  float* covp = fws + COVP_OFF;
  float* mean = fws + MEAN_OFF;
  int* idx = (int*)(fws + IDX_OFF);
  int* inv = (int*)(fws + INV_OFF);
  float* covs = fws + COVS_OFF;
  float* wT   = fws + WT_OFF;
  float* gT   = fws + GT2_OFF;
  float* dT   = fws + DT2_OFF;
  float* uT   = fws + UT2_OFF;
  float* pT   = fws + PT2_OFF;

  k_prep_wt<<<48, 256, 0, stream>>>(qkv_w, wT);
  k_pool_conv<<<1024, 256, 0, stream>>>(x, wT, pre);
  k_dw3x3_zero<<<12288, 256, 0, stream>>>(pre, lce_w, qkv);
  k_prep2<<<16, 256, 0, stream>>>(gating_w, down_w, up_w, proj_w, gT, dT, uT, pT);
  k_mean<<<256, 256, 0, stream>>>(qkv, mean);
  k_covpart<<<512, 256, 0, stream>>>(qkv, mean, covp);
  k_covred<<<64, 256, 0, stream>>>(covp, covs);
  k_simsort<<<4, 256, 0, stream>>>(covs, idx, inv);
  k_attn<<<4096, 128, 0, stream>>>(qkv, idx, rel_h, rel_w, gate_w, gate_b, temp, attn);
  k_post<<<1024, 256, 0, stream>>>(attn, qkv, gT, gating_b, dT, down_b,
                                   uT, up_b, pT, out3);
  k_final<<<2048, 256, 0, stream>>>(out3, lp_w, lp_b, outp);
  (void)inv;
}